// Round 3
// baseline (698.436 us; speedup 1.0000x reference)
//
#include <hip/hip_runtime.h>
#include <hip/hip_bf16.h>

// ---------- bf16 helpers (OCP bf16 = fp32 upper 16 bits) ----------
__device__ __forceinline__ float bf2f(unsigned short u) {
  union { unsigned int i; float f; } v; v.i = ((unsigned int)u) << 16; return v.f;
}
__device__ __forceinline__ unsigned short f2bf(float f) {
  union { float f; unsigned int i; } v; v.f = f;
  unsigned int x = v.i;
  return (unsigned short)((x + 0x7fffu + ((x >> 16) & 1u)) >> 16);  // RNE
}

// ---------- 0. per-tensor runtime dtype detection ----------
// flags[0]=x_fp32  flags[1]=int64  flags[2]=w1_fp32  flags[3]=w2_fp32
// flags[4]=b1_fp32 flags[5]=b2_fp32
// Probe: read n ushorts; count "wild" bf16 exponents (e<96 or e>159).
// bf16 N(0,1)-scale data: ~0 wild. fp32 data: low-half words are random
// mantissa bits -> ~37.5% of all probed words wild. Threshold: >n/8.
__global__ __launch_bounds__(256) void detect_all_k(
    const unsigned short* __restrict__ xu,  const int* __restrict__ ei,
    const unsigned short* __restrict__ w1u, const unsigned short* __restrict__ w2u,
    const unsigned short* __restrict__ b1u, const unsigned short* __restrict__ b2u,
    int* __restrict__ flags) {
  __shared__ int s_cnt;
  if (threadIdx.x == 0) s_cnt = 0;
  __syncthreads();
  const int b = blockIdx.x;
  int cnt = 0;
  if (b == 1) {  // int width: high words of int64 positives are all zero
    for (int i = threadIdx.x; i < 4096; i += 256)
      if (ei[2 * i + 1] == 0) cnt++;
    atomicAdd(&s_cnt, cnt);
    __syncthreads();
    if (threadIdx.x == 0) flags[1] = (s_cnt > 2048) ? 1 : 0;
    return;
  }
  const unsigned short* p; int n; int fi;
  if (b == 0)      { p = xu;  n = 16384; fi = 0; }
  else if (b == 2) { p = w1u; n = 16384; fi = 2; }
  else if (b == 3) { p = w2u; n = 16384; fi = 3; }
  else if (b == 4) { p = b1u; n = 128;   fi = 4; }
  else             { p = b2u; n = 128;   fi = 5; }
  for (int i = threadIdx.x; i < n; i += 256) {
    int e = (p[i] >> 7) & 0xFF;
    if (e < 96 || e > 159) cnt++;
  }
  atomicAdd(&s_cnt, cnt);
  __syncthreads();
  if (threadIdx.x == 0) flags[fi] = (s_cnt * 8 > n) ? 1 : 0;
}

// ---------- param converts (per-tensor flag index) ----------
__global__ void cvt_w_k(const void* __restrict__ src, unsigned short* __restrict__ dst,
                        int n, const int* __restrict__ flags, int fi) {
  int i = blockIdx.x * blockDim.x + threadIdx.x;
  if (i >= n) return;
  dst[i] = flags[fi] ? f2bf(((const float*)src)[i]) : ((const unsigned short*)src)[i];
}
__global__ void cvt_b_k(const void* __restrict__ src, float* __restrict__ dst,
                        int n, const int* __restrict__ flags, int fi) {
  int i = blockIdx.x * blockDim.x + threadIdx.x;
  if (i >= n) return;
  dst[i] = flags[fi] ? ((const float*)src)[i] : bf2f(((const unsigned short*)src)[i]);
}

// ---------- 1. degree count (in-degree at dst) ----------
__global__ void count_deg_k(const int* __restrict__ ei, int* __restrict__ deg, int E,
                            const int* __restrict__ flags) {
  int e = blockIdx.x * blockDim.x + threadIdx.x;
  if (e >= E) return;
  int d = flags[1] ? ei[2 * (E + e)] : ei[E + e];  // int64: low word of element E+e
  atomicAdd(&deg[d], 1);
}

// ---------- 2. exclusive scan of deg -> rowptr; dinv = rsqrt(deg+1) ----------
__global__ __launch_bounds__(1024) void scan_deg_k(const int* __restrict__ deg,
                                                   int* __restrict__ rowptr,
                                                   float* __restrict__ dinv, int N) {
  __shared__ int wsum[16];
  const int tid = threadIdx.x;
  const int lane = tid & 63;
  const int wave = tid >> 6;
  int carry = 0;
  for (int base = 0; base < N; base += 8192) {
    int idx0 = base + tid * 8;
    int v[8];
    #pragma unroll
    for (int j = 0; j < 8; ++j) { int i = idx0 + j; v[j] = (i < N) ? deg[i] : 0; }
    #pragma unroll
    for (int j = 1; j < 8; ++j) v[j] += v[j - 1];
    int tot = v[7];
    int sc = tot;
    #pragma unroll
    for (int off = 1; off < 64; off <<= 1) {
      int n = __shfl_up(sc, off, 64);
      if (lane >= off) sc += n;
    }
    if (lane == 63) wsum[wave] = sc;
    __syncthreads();
    int wprefix = 0, chunktot = 0;
    #pragma unroll
    for (int w = 0; w < 16; ++w) { int s = wsum[w]; if (w < wave) wprefix += s; chunktot += s; }
    int excl = carry + wprefix + (sc - tot);
    #pragma unroll
    for (int j = 0; j < 8; ++j) {
      int i = idx0 + j;
      if (i < N) {
        int prev = j ? v[j - 1] : 0;
        rowptr[i] = excl + prev;
        dinv[i] = rsqrtf((float)(v[j] - prev + 1));  // +1 self-loop
      }
    }
    carry += chunktot;
    __syncthreads();
  }
  if (tid == 0) rowptr[N] = carry;
}

// ---------- 3. counting-sort edges by dst ----------
__global__ void scatter_k(const int* __restrict__ ei, int* __restrict__ cursor,
                          int* __restrict__ ssrc, int E, const int* __restrict__ flags) {
  int e = blockIdx.x * blockDim.x + threadIdx.x;
  if (e >= E) return;
  int s, d;
  if (flags[1]) { s = ei[2 * e]; d = ei[2 * (E + e)]; }
  else          { s = ei[e];     d = ei[E + e]; }
  int pos = atomicAdd(&cursor[d], 1);
  ssrc[pos] = s;
}

// ---------- 4. GEMM: XW[N,128] = X[N,128] @ W[128,128] (W bf16-converted, fp32 acc) ----------
// xmode: 1 -> X is fp32 for sure (layer 2); 0 -> consult flags[0]
__global__ __launch_bounds__(256) void gemm_k(const void* __restrict__ X,
                                              const unsigned short* __restrict__ Wb,
                                              float* __restrict__ XW, int N,
                                              const int* __restrict__ flags, int xmode) {
  __shared__ unsigned short Wl[128 * 128];            // 32 KB bf16
  __shared__ __align__(16) float Xt[128 * 36];        // 18 KB, transposed [k][r], pad 36
  const int tid = threadIdx.x;
  for (int t = tid; t < 4096; t += 256)               // stage W (ushort4 = 8 B)
    ((ushort4*)Wl)[t] = ((const ushort4*)Wb)[t];
  const int xf32 = xmode ? 1 : flags[0];
  const long long row0 = (long long)blockIdx.x * 32;
  for (int t = tid; t < 4096; t += 256) {             // stage X transposed
    int r = t >> 7, c = t & 127;
    long long row = row0 + r;
    float v = 0.f;
    if (row < N) {
      long long gi = row * 128 + c;
      v = xf32 ? ((const float*)X)[gi] : bf2f(((const unsigned short*)X)[gi]);
    }
    Xt[c * 36 + r] = v;
  }
  __syncthreads();
  const int col4 = (tid & 31) * 4;   // 4 consecutive output cols
  const int rq = tid >> 5;           // row quad: rows rq*4 .. rq*4+3
  float4 acc[4];
  #pragma unroll
  for (int i = 0; i < 4; ++i) acc[i] = make_float4(0.f, 0.f, 0.f, 0.f);
  #pragma unroll 4
  for (int k = 0; k < 128; ++k) {
    float4 xv = *(const float4*)&Xt[k * 36 + rq * 4];              // 4 rows
    ushort4 w4 = *(const ushort4*)&Wl[k * 128 + col4];             // 4 cols
    float wx = bf2f(w4.x), wy = bf2f(w4.y), wz = bf2f(w4.z), ww = bf2f(w4.w);
    acc[0].x = fmaf(xv.x, wx, acc[0].x); acc[0].y = fmaf(xv.x, wy, acc[0].y);
    acc[0].z = fmaf(xv.x, wz, acc[0].z); acc[0].w = fmaf(xv.x, ww, acc[0].w);
    acc[1].x = fmaf(xv.y, wx, acc[1].x); acc[1].y = fmaf(xv.y, wy, acc[1].y);
    acc[1].z = fmaf(xv.y, wz, acc[1].z); acc[1].w = fmaf(xv.y, ww, acc[1].w);
    acc[2].x = fmaf(xv.z, wx, acc[2].x); acc[2].y = fmaf(xv.z, wy, acc[2].y);
    acc[2].z = fmaf(xv.z, wz, acc[2].z); acc[2].w = fmaf(xv.z, ww, acc[2].w);
    acc[3].x = fmaf(xv.w, wx, acc[3].x); acc[3].y = fmaf(xv.w, wy, acc[3].y);
    acc[3].z = fmaf(xv.w, wz, acc[3].z); acc[3].w = fmaf(xv.w, ww, acc[3].w);
  }
  #pragma unroll
  for (int i = 0; i < 4; ++i) {
    long long row = row0 + rq * 4 + i;
    if (row < N) *(float4*)&XW[row * 128 + col4] = acc[i];
  }
}

// ---------- 5. aggregate: H[i] = act(dinv[i]*sum(dinv[s]*XW[s]) + dinv[i]^2*XW[i] + b) ----------
__global__ __launch_bounds__(256) void aggregate_k(const float* __restrict__ XW,
    const int* __restrict__ rowptr, const int* __restrict__ ssrc,
    const float* __restrict__ dinv, const float* __restrict__ bias,
    float* __restrict__ H, int N, int relu) {
  int wid = (blockIdx.x * 256 + threadIdx.x) >> 6;  // one wave per node
  if (wid >= N) return;
  int lane = threadIdx.x & 63;                      // lane owns features 2*lane, 2*lane+1
  int beg = rowptr[wid], end = rowptr[wid + 1];
  float di = dinv[wid];
  float ax = 0.f, ay = 0.f;
  int idx = beg;
  for (; idx + 1 < end; idx += 2) {
    int s0 = ssrc[idx], s1 = ssrc[idx + 1];
    float w0 = dinv[s0], w1 = dinv[s1];
    float2 v0 = *(const float2*)&XW[(long long)s0 * 128 + lane * 2];
    float2 v1 = *(const float2*)&XW[(long long)s1 * 128 + lane * 2];
    ax += w0 * v0.x + w1 * v1.x;
    ay += w0 * v0.y + w1 * v1.y;
  }
  if (idx < end) {
    int s0 = ssrc[idx];
    float w0 = dinv[s0];
    float2 v0 = *(const float2*)&XW[(long long)s0 * 128 + lane * 2];
    ax += w0 * v0.x;
    ay += w0 * v0.y;
  }
  float2 sv = *(const float2*)&XW[(long long)wid * 128 + lane * 2];
  float ox = di * ax + di * di * sv.x;
  float oy = di * ay + di * di * sv.y;
  if (bias) { ox += bias[lane * 2]; oy += bias[lane * 2 + 1]; }
  if (relu) { ox = fmaxf(ox, 0.f); oy = fmaxf(oy, 0.f); }
  *(float2*)&H[(long long)wid * 128 + lane * 2] = make_float2(ox, oy);
}

// ---------- 6. mean-pool per graph + b2, fp32 out ----------
__global__ __launch_bounds__(128) void pool_k(const float* __restrict__ H,
    const int* __restrict__ batch, const float* __restrict__ B2,
    float* __restrict__ out, int N, const int* __restrict__ flags) {
  __shared__ int sb[2];
  int g = blockIdx.x;
  int i64 = flags[1];
  if (threadIdx.x < 2) {
    int target = g + threadIdx.x;
    int lo = 0, hi = N;
    while (lo < hi) {
      int mid = (lo + hi) >> 1;
      int bv = i64 ? batch[2 * mid] : batch[mid];
      if (bv < target) lo = mid + 1; else hi = mid;
    }
    sb[threadIdx.x] = lo;
  }
  __syncthreads();
  int beg = sb[0], end = sb[1];
  int f = threadIdx.x;
  float sum = 0.f;
  for (int n = beg; n < end; ++n) sum += H[(long long)n * 128 + f];
  int cnt = end - beg;
  float res = 0.f;
  if (cnt > 0) res = sum / (float)cnt + B2[f];  // mean(h+b2) == mean(h)+b2
  out[g * 128 + f] = res;                       // OUTPUT = fp32
}

extern "C" void kernel_launch(void* const* d_in, const int* in_sizes, int n_in,
                              void* d_out, int out_size, void* d_ws, size_t ws_size,
                              hipStream_t stream) {
  const int N = in_sizes[0] / 128;   // 50000
  const int E = in_sizes[1] / 2;     // 800000
  const int G = out_size / 128;      // 64

  const void* X  = d_in[0];                       // fp32 (or bf16) [N,128]
  const int*  EI = (const int*)d_in[1];           // int32 or int64 [2,E]
  const int*  BA = (const int*)d_in[2];           // int32 or int64 [N] sorted
  const void* W1 = d_in[3];
  const void* B1 = d_in[4];
  const void* W2 = d_in[5];
  const void* B2 = d_in[6];
  float* OUT = (float*)d_out;                     // fp32 [G,128]

  char* ws = (char*)d_ws;
  size_t o = 0;
  auto alloc = [&](size_t b) { size_t r = o; o += (b + 255) & ~(size_t)255; return r; };
  int*   flags  = (int*)(ws + alloc(256));
  unsigned short* w1b = (unsigned short*)(ws + alloc(16384 * 2));
  unsigned short* w2b = (unsigned short*)(ws + alloc(16384 * 2));
  float* b1f    = (float*)(ws + alloc(128 * 4));
  float* b2f    = (float*)(ws + alloc(128 * 4));
  int*   deg    = (int*)(ws + alloc((size_t)N * 4));
  int*   rowptr = (int*)(ws + alloc((size_t)(N + 1) * 4));
  int*   cursor = (int*)(ws + alloc((size_t)(N + 1) * 4));
  int*   ssrc   = (int*)(ws + alloc((size_t)E * 4));
  float* dinv   = (float*)(ws + alloc((size_t)N * 4));
  float* xw     = (float*)(ws + alloc((size_t)N * 128 * 4));
  float* h1     = (float*)(ws + alloc((size_t)N * 128 * 4));
  float* h2     = h1;  // h1 dead after gemm2 stages it; safe alias

  const int TB = 256;
  // per-tensor dtype probes, then param converts
  detect_all_k<<<6, 256, 0, stream>>>((const unsigned short*)X, EI,
                                      (const unsigned short*)W1, (const unsigned short*)W2,
                                      (const unsigned short*)B1, (const unsigned short*)B2,
                                      flags);
  cvt_w_k<<<64, 256, 0, stream>>>(W1, w1b, 16384, flags, 2);
  cvt_w_k<<<64, 256, 0, stream>>>(W2, w2b, 16384, flags, 3);
  cvt_b_k<<<1, 128, 0, stream>>>(B1, b1f, 128, flags, 4);
  cvt_b_k<<<1, 128, 0, stream>>>(B2, b2f, 128, flags, 5);

  // CSR build (shared by both layers)
  hipMemsetAsync(deg, 0, (size_t)N * 4, stream);
  count_deg_k<<<(E + TB - 1) / TB, TB, 0, stream>>>(EI, deg, E, flags);
  scan_deg_k<<<1, 1024, 0, stream>>>(deg, rowptr, dinv, N);
  hipMemcpyAsync(cursor, rowptr, (size_t)N * 4, hipMemcpyDeviceToDevice, stream);
  scatter_k<<<(E + TB - 1) / TB, TB, 0, stream>>>(EI, cursor, ssrc, E, flags);

  dim3 ggrid((N + 31) / 32);
  dim3 agrid((N * 64 + 255) / 256);

  // layer 1
  gemm_k<<<ggrid, 256, 0, stream>>>(X, w1b, xw, N, flags, 0);
  aggregate_k<<<agrid, 256, 0, stream>>>(xw, rowptr, ssrc, dinv, b1f, h1, N, 1);
  // layer 2
  gemm_k<<<ggrid, 256, 0, stream>>>(h1, w2b, xw, N, flags, 1);
  aggregate_k<<<agrid, 256, 0, stream>>>(xw, rowptr, ssrc, dinv, (const float*)nullptr, h2, N, 0);
  // pool
  pool_k<<<G, 128, 0, stream>>>(h2, BA, b2f, OUT, N, flags);
}

// Round 4
// 459.321 us; speedup vs baseline: 1.5206x; 1.5206x over previous
//
#include <hip/hip_runtime.h>
#include <hip/hip_bf16.h>

// ---------- bf16 helpers (OCP bf16 = fp32 upper 16 bits) ----------
__device__ __forceinline__ float bf2f(unsigned short u) {
  union { unsigned int i; float f; } v; v.i = ((unsigned int)u) << 16; return v.f;
}
__device__ __forceinline__ unsigned short f2bf(float f) {
  union { float f; unsigned int i; } v; v.f = f;
  unsigned int x = v.i;
  return (unsigned short)((x + 0x7fffu + ((x >> 16) & 1u)) >> 16);  // RNE
}

// ---------- 0. per-tensor runtime dtype detection ----------
// flags[0]=x_fp32  flags[1]=int64  flags[2]=w1_fp32  flags[3]=w2_fp32
// flags[4]=b1_fp32 flags[5]=b2_fp32
__global__ __launch_bounds__(256) void detect_all_k(
    const unsigned short* __restrict__ xu,  const int* __restrict__ ei,
    const unsigned short* __restrict__ w1u, const unsigned short* __restrict__ w2u,
    const unsigned short* __restrict__ b1u, const unsigned short* __restrict__ b2u,
    int* __restrict__ flags) {
  __shared__ int s_cnt;
  if (threadIdx.x == 0) s_cnt = 0;
  __syncthreads();
  const int b = blockIdx.x;
  int cnt = 0;
  if (b == 1) {  // int width: high words of int64 positives are all zero
    for (int i = threadIdx.x; i < 4096; i += 256)
      if (ei[2 * i + 1] == 0) cnt++;
    atomicAdd(&s_cnt, cnt);
    __syncthreads();
    if (threadIdx.x == 0) flags[1] = (s_cnt > 2048) ? 1 : 0;
    return;
  }
  const unsigned short* p; int n; int fi;
  if (b == 0)      { p = xu;  n = 16384; fi = 0; }
  else if (b == 2) { p = w1u; n = 16384; fi = 2; }
  else if (b == 3) { p = w2u; n = 16384; fi = 3; }
  else if (b == 4) { p = b1u; n = 128;   fi = 4; }
  else             { p = b2u; n = 128;   fi = 5; }
  for (int i = threadIdx.x; i < n; i += 256) {
    int e = (p[i] >> 7) & 0xFF;
    if (e < 96 || e > 159) cnt++;   // wild bf16 exponent => this is fp32 data
  }
  atomicAdd(&s_cnt, cnt);
  __syncthreads();
  if (threadIdx.x == 0) flags[fi] = (s_cnt * 8 > n) ? 1 : 0;
}

// ---------- param convert: anything -> fp32 ----------
__global__ void cvt_f_k(const void* __restrict__ src, float* __restrict__ dst,
                        int n, const int* __restrict__ flags, int fi) {
  int i = blockIdx.x * blockDim.x + threadIdx.x;
  if (i >= n) return;
  dst[i] = flags[fi] ? ((const float*)src)[i] : bf2f(((const unsigned short*)src)[i]);
}

// ---------- 1. degree count (in-degree at dst) ----------
__global__ void count_deg_k(const int* __restrict__ ei, int* __restrict__ deg, int E,
                            const int* __restrict__ flags) {
  int e = blockIdx.x * blockDim.x + threadIdx.x;
  if (e >= E) return;
  int d = flags[1] ? ei[2 * (E + e)] : ei[E + e];
  atomicAdd(&deg[d], 1);
}

// ---------- 2. exclusive scan of deg -> rowptr; dinv = rsqrt(deg+1) ----------
__global__ __launch_bounds__(1024) void scan_deg_k(const int* __restrict__ deg,
                                                   int* __restrict__ rowptr,
                                                   float* __restrict__ dinv, int N) {
  __shared__ int wsum[16];
  const int tid = threadIdx.x;
  const int lane = tid & 63;
  const int wave = tid >> 6;
  int carry = 0;
  for (int base = 0; base < N; base += 8192) {
    int idx0 = base + tid * 8;
    int v[8];
    #pragma unroll
    for (int j = 0; j < 8; ++j) { int i = idx0 + j; v[j] = (i < N) ? deg[i] : 0; }
    #pragma unroll
    for (int j = 1; j < 8; ++j) v[j] += v[j - 1];
    int tot = v[7];
    int sc = tot;
    #pragma unroll
    for (int off = 1; off < 64; off <<= 1) {
      int n = __shfl_up(sc, off, 64);
      if (lane >= off) sc += n;
    }
    if (lane == 63) wsum[wave] = sc;
    __syncthreads();
    int wprefix = 0, chunktot = 0;
    #pragma unroll
    for (int w = 0; w < 16; ++w) { int s = wsum[w]; if (w < wave) wprefix += s; chunktot += s; }
    int excl = carry + wprefix + (sc - tot);
    #pragma unroll
    for (int j = 0; j < 8; ++j) {
      int i = idx0 + j;
      if (i < N) {
        int prev = j ? v[j - 1] : 0;
        rowptr[i] = excl + prev;
        dinv[i] = rsqrtf((float)(v[j] - prev + 1));  // +1 self-loop
      }
    }
    carry += chunktot;
    __syncthreads();
  }
  if (tid == 0) rowptr[N] = carry;
}

// ---------- 3. counting-sort edges by dst ----------
__global__ void scatter_k(const int* __restrict__ ei, int* __restrict__ cursor,
                          int* __restrict__ ssrc, int E, const int* __restrict__ flags) {
  int e = blockIdx.x * blockDim.x + threadIdx.x;
  if (e >= E) return;
  int s, d;
  if (flags[1]) { s = ei[2 * e]; d = ei[2 * (E + e)]; }
  else          { s = ei[e];     d = ei[E + e]; }
  int pos = atomicAdd(&cursor[d], 1);
  ssrc[pos] = s;
}

// ---------- 4. GEMM: XWb[N,128](bf16) = X[N,128](fp32) @ W[128,128](fp32) ----------
// Two k-phases of 64 so fp32 W tile fits LDS (32KB W + 9.2KB Xt = 41KB).
// xmode: 1 -> X definitely fp32 (layer 2); 0 -> consult flags[0]
__global__ __launch_bounds__(256) void gemm_k(const void* __restrict__ X,
                                              const float* __restrict__ Wf,
                                              unsigned short* __restrict__ XWb, int N,
                                              const int* __restrict__ flags, int xmode) {
  __shared__ __align__(16) float Wl[64 * 128];   // 32 KB (one 64-k slab, fp32)
  __shared__ __align__(16) float Xt[64 * 36];    // 9.2 KB transposed [k'][r], pad 36
  const int tid = threadIdx.x;
  const int xf32 = xmode ? 1 : flags[0];
  const long long row0 = (long long)blockIdx.x * 32;
  const int col4 = (tid & 31) * 4;   // 4 consecutive output cols
  const int rq = tid >> 5;           // row quad: rows rq*4 .. rq*4+3
  float4 acc[4];
  #pragma unroll
  for (int i = 0; i < 4; ++i) acc[i] = make_float4(0.f, 0.f, 0.f, 0.f);

  for (int p = 0; p < 2; ++p) {
    if (p) __syncthreads();          // previous phase's LDS reads done
    // stage W slab: rows k=p*64..p*64+63, all 128 cols (float4 coalesced)
    for (int t = tid; t < 2048; t += 256) {
      int kk = t >> 5, c4 = (t & 31) * 4;
      *(float4*)&Wl[kk * 128 + c4] = *(const float4*)&Wf[(p * 64 + kk) * 128 + c4];
    }
    // stage X tile transposed: 32 rows x 64 k'
    for (int t = tid; t < 2048; t += 256) {
      int r = t >> 6, kk = t & 63;
      long long row = row0 + r;
      float v = 0.f;
      if (row < N) {
        long long gi = row * 128 + p * 64 + kk;
        v = xf32 ? ((const float*)X)[gi] : bf2f(((const unsigned short*)X)[gi]);
      }
      Xt[kk * 36 + r] = v;
    }
    __syncthreads();
    #pragma unroll 4
    for (int k = 0; k < 64; ++k) {
      float4 xv = *(const float4*)&Xt[k * 36 + rq * 4];
      float4 wv = *(const float4*)&Wl[k * 128 + col4];
      acc[0].x = fmaf(xv.x, wv.x, acc[0].x); acc[0].y = fmaf(xv.x, wv.y, acc[0].y);
      acc[0].z = fmaf(xv.x, wv.z, acc[0].z); acc[0].w = fmaf(xv.x, wv.w, acc[0].w);
      acc[1].x = fmaf(xv.y, wv.x, acc[1].x); acc[1].y = fmaf(xv.y, wv.y, acc[1].y);
      acc[1].z = fmaf(xv.y, wv.z, acc[1].z); acc[1].w = fmaf(xv.y, wv.w, acc[1].w);
      acc[2].x = fmaf(xv.z, wv.x, acc[2].x); acc[2].y = fmaf(xv.z, wv.y, acc[2].y);
      acc[2].z = fmaf(xv.z, wv.z, acc[2].z); acc[2].w = fmaf(xv.z, wv.w, acc[2].w);
      acc[3].x = fmaf(xv.w, wv.x, acc[3].x); acc[3].y = fmaf(xv.w, wv.y, acc[3].y);
      acc[3].z = fmaf(xv.w, wv.z, acc[3].z); acc[3].w = fmaf(xv.w, wv.w, acc[3].w);
    }
  }
  #pragma unroll
  for (int i = 0; i < 4; ++i) {
    long long row = row0 + rq * 4 + i;
    if (row < N) {
      ushort4 u;
      u.x = f2bf(acc[i].x); u.y = f2bf(acc[i].y);
      u.z = f2bf(acc[i].z); u.w = f2bf(acc[i].w);
      *(ushort4*)&XWb[row * 128 + col4] = u;   // bf16 store: halves gather traffic
    }
  }
}

// ---------- 5. aggregate: H[i] = act(dinv[i]*sum(dinv[s]*XW[s]) + dinv[i]^2*XW[i] + b) ----------
// XW is bf16 (ushort2 per lane = 256 B/row gather), H fp32.
__global__ __launch_bounds__(256) void aggregate_k(const unsigned short* __restrict__ XWb,
    const int* __restrict__ rowptr, const int* __restrict__ ssrc,
    const float* __restrict__ dinv, const float* __restrict__ bias,
    float* __restrict__ H, int N, int relu) {
  int wid = (blockIdx.x * 256 + threadIdx.x) >> 6;  // one wave per node
  if (wid >= N) return;
  int lane = threadIdx.x & 63;                      // lane owns features 2*lane, 2*lane+1
  int beg = rowptr[wid], end = rowptr[wid + 1];
  float di = dinv[wid];
  float ax = 0.f, ay = 0.f;
  int idx = beg;
  for (; idx + 1 < end; idx += 2) {
    int s0 = ssrc[idx], s1 = ssrc[idx + 1];
    float w0 = dinv[s0], w1 = dinv[s1];
    ushort2 u0 = *(const ushort2*)&XWb[(long long)s0 * 128 + lane * 2];
    ushort2 u1 = *(const ushort2*)&XWb[(long long)s1 * 128 + lane * 2];
    ax += w0 * bf2f(u0.x) + w1 * bf2f(u1.x);
    ay += w0 * bf2f(u0.y) + w1 * bf2f(u1.y);
  }
  if (idx < end) {
    int s0 = ssrc[idx];
    float w0 = dinv[s0];
    ushort2 u0 = *(const ushort2*)&XWb[(long long)s0 * 128 + lane * 2];
    ax += w0 * bf2f(u0.x);
    ay += w0 * bf2f(u0.y);
  }
  ushort2 su = *(const ushort2*)&XWb[(long long)wid * 128 + lane * 2];
  float ox = di * ax + di * di * bf2f(su.x);
  float oy = di * ay + di * di * bf2f(su.y);
  if (bias) { ox += bias[lane * 2]; oy += bias[lane * 2 + 1]; }
  if (relu) { ox = fmaxf(ox, 0.f); oy = fmaxf(oy, 0.f); }
  *(float2*)&H[(long long)wid * 128 + lane * 2] = make_float2(ox, oy);
}

// ---------- 6a. pool phase A: per-wave run-length partial sums + atomic flush ----------
__global__ __launch_bounds__(256) void pool_partial_k(const float* __restrict__ H,
    const int* __restrict__ batch, float* __restrict__ acc, int N,
    const int* __restrict__ flags) {
  const int i64 = flags[1];
  const int lane = threadIdx.x & 63;
  const int w = threadIdx.x >> 6;
  const int chunk = (N + gridDim.x - 1) / gridDim.x;
  const int bstart = blockIdx.x * chunk;
  const int bend = min(bstart + chunk, N);
  const int sub = (chunk + 3) / 4;
  const int s = bstart + w * sub;
  const int e = min(s + sub, bend);
  if (s >= e) return;
  float ax = 0.f, ay = 0.f;
  int curg = i64 ? batch[2 * s] : batch[s];
  for (int n = s; n < e; ++n) {
    int g = i64 ? batch[2 * n] : batch[n];   // sorted; uniform per wave
    if (g != curg) {
      atomicAdd(&acc[curg * 128 + lane * 2], ax);
      atomicAdd(&acc[curg * 128 + lane * 2 + 1], ay);
      ax = ay = 0.f; curg = g;
    }
    float2 v = *(const float2*)&H[(long long)n * 128 + lane * 2];
    ax += v.x; ay += v.y;
  }
  atomicAdd(&acc[curg * 128 + lane * 2], ax);
  atomicAdd(&acc[curg * 128 + lane * 2 + 1], ay);
}

// ---------- 6b. pool finalize: mean + b2 ----------
__global__ __launch_bounds__(128) void pool_final_k(const float* __restrict__ acc,
    const int* __restrict__ batch, const float* __restrict__ B2,
    float* __restrict__ out, int N, const int* __restrict__ flags) {
  __shared__ int sb[2];
  int g = blockIdx.x;
  int i64 = flags[1];
  if (threadIdx.x < 2) {
    int target = g + threadIdx.x;
    int lo = 0, hi = N;
    while (lo < hi) {
      int mid = (lo + hi) >> 1;
      int bv = i64 ? batch[2 * mid] : batch[mid];
      if (bv < target) lo = mid + 1; else hi = mid;
    }
    sb[threadIdx.x] = lo;
  }
  __syncthreads();
  int cnt = sb[1] - sb[0];
  int f = threadIdx.x;
  float res = 0.f;
  if (cnt > 0) res = acc[g * 128 + f] / (float)cnt + B2[f];
  out[g * 128 + f] = res;
}

extern "C" void kernel_launch(void* const* d_in, const int* in_sizes, int n_in,
                              void* d_out, int out_size, void* d_ws, size_t ws_size,
                              hipStream_t stream) {
  const int N = in_sizes[0] / 128;   // 50000
  const int E = in_sizes[1] / 2;     // 800000
  const int G = out_size / 128;      // 64

  const void* X  = d_in[0];                       // fp32 [N,128]
  const int*  EI = (const int*)d_in[1];           // int32 or int64 [2,E]
  const int*  BA = (const int*)d_in[2];           // int32 or int64 [N] sorted
  const void* W1 = d_in[3];
  const void* B1 = d_in[4];
  const void* W2 = d_in[5];
  const void* B2 = d_in[6];
  float* OUT = (float*)d_out;                     // fp32 [G,128]

  char* ws = (char*)d_ws;
  size_t o = 0;
  auto alloc = [&](size_t b) { size_t r = o; o += (b + 255) & ~(size_t)255; return r; };
  int*   flags  = (int*)(ws + alloc(256));
  float* w1f    = (float*)(ws + alloc(16384 * 4));
  float* w2f    = (float*)(ws + alloc(16384 * 4));
  float* b1f    = (float*)(ws + alloc(128 * 4));
  float* b2f    = (float*)(ws + alloc(128 * 4));
  float* acc    = (float*)(ws + alloc((size_t)G * 128 * 4));
  int*   deg    = (int*)(ws + alloc((size_t)N * 4));
  int*   rowptr = (int*)(ws + alloc((size_t)(N + 1) * 4));
  int*   cursor = (int*)(ws + alloc((size_t)(N + 1) * 4));
  int*   ssrc   = (int*)(ws + alloc((size_t)E * 4));
  float* dinv   = (float*)(ws + alloc((size_t)N * 4));
  unsigned short* xwb = (unsigned short*)(ws + alloc((size_t)N * 128 * 2));  // bf16
  float* h1     = (float*)(ws + alloc((size_t)N * 128 * 4));
  float* h2     = h1;  // h1 dead after gemm2 stages it; safe alias

  const int TB = 256;
  // dtype probes + param converts (all params normalized to fp32)
  detect_all_k<<<6, 256, 0, stream>>>((const unsigned short*)X, EI,
                                      (const unsigned short*)W1, (const unsigned short*)W2,
                                      (const unsigned short*)B1, (const unsigned short*)B2,
                                      flags);
  cvt_f_k<<<64, 256, 0, stream>>>(W1, w1f, 16384, flags, 2);
  cvt_f_k<<<64, 256, 0, stream>>>(W2, w2f, 16384, flags, 3);
  cvt_f_k<<<1, 128, 0, stream>>>(B1, b1f, 128, flags, 4);
  cvt_f_k<<<1, 128, 0, stream>>>(B2, b2f, 128, flags, 5);

  // CSR build (shared by both layers)
  hipMemsetAsync(deg, 0, (size_t)N * 4, stream);
  hipMemsetAsync(acc, 0, (size_t)G * 128 * 4, stream);
  count_deg_k<<<(E + TB - 1) / TB, TB, 0, stream>>>(EI, deg, E, flags);
  scan_deg_k<<<1, 1024, 0, stream>>>(deg, rowptr, dinv, N);
  hipMemcpyAsync(cursor, rowptr, (size_t)N * 4, hipMemcpyDeviceToDevice, stream);
  scatter_k<<<(E + TB - 1) / TB, TB, 0, stream>>>(EI, cursor, ssrc, E, flags);

  dim3 ggrid((N + 31) / 32);
  dim3 agrid((N * 64 + 255) / 256);

  // layer 1
  gemm_k<<<ggrid, 256, 0, stream>>>(X, w1f, xwb, N, flags, 0);
  aggregate_k<<<agrid, 256, 0, stream>>>(xwb, rowptr, ssrc, dinv, b1f, h1, N, 1);
  // layer 2
  gemm_k<<<ggrid, 256, 0, stream>>>(h1, w2f, xwb, N, flags, 1);
  aggregate_k<<<agrid, 256, 0, stream>>>(xwb, rowptr, ssrc, dinv, (const float*)nullptr, h2, N, 0);
  // pool (two-phase)
  pool_partial_k<<<512, 256, 0, stream>>>(h2, BA, acc, N, flags);
  pool_final_k<<<G, 128, 0, stream>>>(acc, BA, b2f, OUT, N, flags);
}

// Round 5
// 392.936 us; speedup vs baseline: 1.7775x; 1.1689x over previous
//
#include <hip/hip_runtime.h>
#include <hip/hip_bf16.h>

// ---------- bf16 helpers (OCP bf16 = fp32 upper 16 bits) ----------
__device__ __forceinline__ float bf2f(unsigned short u) {
  union { unsigned int i; float f; } v; v.i = ((unsigned int)u) << 16; return v.f;
}
__device__ __forceinline__ unsigned short f2bf(float f) {
  union { float f; unsigned int i; } v; v.f = f;
  unsigned int x = v.i;
  return (unsigned short)((x + 0x7fffu + ((x >> 16) & 1u)) >> 16);  // RNE
}

// ---------- 0. per-tensor runtime dtype detection ----------
// flags[0]=x_fp32  flags[1]=int64  flags[2]=w1_fp32  flags[3]=w2_fp32
// flags[4]=b1_fp32 flags[5]=b2_fp32
__global__ __launch_bounds__(256) void detect_all_k(
    const unsigned short* __restrict__ xu,  const int* __restrict__ ei,
    const unsigned short* __restrict__ w1u, const unsigned short* __restrict__ w2u,
    const unsigned short* __restrict__ b1u, const unsigned short* __restrict__ b2u,
    int* __restrict__ flags) {
  __shared__ int s_cnt;
  if (threadIdx.x == 0) s_cnt = 0;
  __syncthreads();
  const int b = blockIdx.x;
  int cnt = 0;
  if (b == 1) {  // int width: high words of int64 positives are all zero
    for (int i = threadIdx.x; i < 4096; i += 256)
      if (ei[2 * i + 1] == 0) cnt++;
    atomicAdd(&s_cnt, cnt);
    __syncthreads();
    if (threadIdx.x == 0) flags[1] = (s_cnt > 2048) ? 1 : 0;
    return;
  }
  const unsigned short* p; int n; int fi;
  if (b == 0)      { p = xu;  n = 16384; fi = 0; }
  else if (b == 2) { p = w1u; n = 16384; fi = 2; }
  else if (b == 3) { p = w2u; n = 16384; fi = 3; }
  else if (b == 4) { p = b1u; n = 128;   fi = 4; }
  else             { p = b2u; n = 128;   fi = 5; }
  for (int i = threadIdx.x; i < n; i += 256) {
    int e = (p[i] >> 7) & 0xFF;
    if (e < 96 || e > 159) cnt++;   // wild bf16 exponent => fp32 data
  }
  atomicAdd(&s_cnt, cnt);
  __syncthreads();
  if (threadIdx.x == 0) flags[fi] = (s_cnt * 8 > n) ? 1 : 0;
}

// ---------- param convert: anything -> fp32 ----------
__global__ void cvt_f_k(const void* __restrict__ src, float* __restrict__ dst,
                        int n, const int* __restrict__ flags, int fi) {
  int i = blockIdx.x * blockDim.x + threadIdx.x;
  if (i >= n) return;
  dst[i] = flags[fi] ? ((const float*)src)[i] : bf2f(((const unsigned short*)src)[i]);
}

// ---------- 1. degree count (in-degree at dst) ----------
__global__ void count_deg_k(const int* __restrict__ ei, int* __restrict__ deg, int E,
                            const int* __restrict__ flags) {
  int e = blockIdx.x * blockDim.x + threadIdx.x;
  if (e >= E) return;
  int d = flags[1] ? ei[2 * (E + e)] : ei[E + e];
  atomicAdd(&deg[d], 1);
}

// ---------- 2. hierarchical exclusive scan (3 tiny kernels) ----------
// S1: per-block (256-elem) sums
__global__ __launch_bounds__(256) void scan1_k(const int* __restrict__ deg,
                                               int* __restrict__ bsum, int N) {
  __shared__ int red[4];
  int i = blockIdx.x * 256 + threadIdx.x;
  int v = (i < N) ? deg[i] : 0;
  int lane = threadIdx.x & 63, w = threadIdx.x >> 6;
  #pragma unroll
  for (int off = 32; off > 0; off >>= 1) v += __shfl_down(v, off, 64);
  if (lane == 0) red[w] = v;
  __syncthreads();
  if (threadIdx.x == 0) bsum[blockIdx.x] = red[0] + red[1] + red[2] + red[3];
}
// S2: single-block scan of block sums -> boff (exclusive); rowptr[N] = total
__global__ __launch_bounds__(256) void scan2_k(const int* __restrict__ bsum,
                                               int* __restrict__ boff,
                                               int* __restrict__ rowptrN, int nb) {
  __shared__ int ws[4];
  const int tid = threadIdx.x, lane = tid & 63, w = tid >> 6;
  int carry = 0;
  for (int base = 0; base < nb; base += 256) {
    int i = base + tid;
    int v = (i < nb) ? bsum[i] : 0;
    int inc = v;
    #pragma unroll
    for (int off = 1; off < 64; off <<= 1) {
      int n = __shfl_up(inc, off, 64);
      if (lane >= off) inc += n;
    }
    if (lane == 63) ws[w] = inc;
    __syncthreads();
    int woff = 0, tot = 0;
    #pragma unroll
    for (int k = 0; k < 4; ++k) { int s = ws[k]; if (k < w) woff += s; tot += s; }
    if (i < nb) boff[i] = carry + woff + inc - v;
    carry += tot;
    __syncthreads();
  }
  if (tid == 0) *rowptrN = carry;
}
// S3: block-local exclusive scan + block offset -> rowptr; dinv = rsqrt(deg+1)
__global__ __launch_bounds__(256) void scan3_k(const int* __restrict__ deg,
                                               const int* __restrict__ boff,
                                               int* __restrict__ rowptr,
                                               float* __restrict__ dinv, int N) {
  __shared__ int ws[4];
  int i = blockIdx.x * 256 + threadIdx.x;
  int lane = threadIdx.x & 63, w = threadIdx.x >> 6;
  int v = (i < N) ? deg[i] : 0;
  int inc = v;
  #pragma unroll
  for (int off = 1; off < 64; off <<= 1) {
    int n = __shfl_up(inc, off, 64);
    if (lane >= off) inc += n;
  }
  if (lane == 63) ws[w] = inc;
  __syncthreads();
  int woff = 0;
  #pragma unroll
  for (int k = 0; k < 4; ++k) if (k < w) woff += ws[k];
  if (i < N) {
    rowptr[i] = boff[blockIdx.x] + woff + inc - v;
    dinv[i] = rsqrtf((float)(v + 1));  // +1 self-loop
  }
}

// ---------- 3. counting-sort edges by dst; payload = {src, dinv[src]} ----------
__global__ void scatter_k(const int* __restrict__ ei, int* __restrict__ cursor,
                          int2* __restrict__ spk, const float* __restrict__ dinv,
                          int E, const int* __restrict__ flags) {
  int e = blockIdx.x * blockDim.x + threadIdx.x;
  if (e >= E) return;
  int s, d;
  if (flags[1]) { s = ei[2 * e]; d = ei[2 * (E + e)]; }
  else          { s = ei[e];     d = ei[E + e]; }
  int pos = atomicAdd(&cursor[d], 1);
  int2 rec; rec.x = s; rec.y = __float_as_int(dinv[s]);
  spk[pos] = rec;
}

// ---------- 4. GEMM: XWb[N,128](bf16) = X[N,128](fp32) @ W[128,128](fp32) ----------
__global__ __launch_bounds__(256) void gemm_k(const void* __restrict__ X,
                                              const float* __restrict__ Wf,
                                              unsigned short* __restrict__ XWb, int N,
                                              const int* __restrict__ flags, int xmode) {
  __shared__ __align__(16) float Wl[64 * 128];   // 32 KB (one 64-k slab, fp32)
  __shared__ __align__(16) float Xt[64 * 36];    // 9.2 KB transposed [k'][r], pad 36
  const int tid = threadIdx.x;
  const int xf32 = xmode ? 1 : flags[0];
  const long long row0 = (long long)blockIdx.x * 32;
  const int col4 = (tid & 31) * 4;
  const int rq = tid >> 5;
  float4 acc[4];
  #pragma unroll
  for (int i = 0; i < 4; ++i) acc[i] = make_float4(0.f, 0.f, 0.f, 0.f);

  for (int p = 0; p < 2; ++p) {
    if (p) __syncthreads();
    for (int t = tid; t < 2048; t += 256) {
      int kk = t >> 5, c4 = (t & 31) * 4;
      *(float4*)&Wl[kk * 128 + c4] = *(const float4*)&Wf[(p * 64 + kk) * 128 + c4];
    }
    for (int t = tid; t < 2048; t += 256) {
      int r = t >> 6, kk = t & 63;
      long long row = row0 + r;
      float v = 0.f;
      if (row < N) {
        long long gi = row * 128 + p * 64 + kk;
        v = xf32 ? ((const float*)X)[gi] : bf2f(((const unsigned short*)X)[gi]);
      }
      Xt[kk * 36 + r] = v;
    }
    __syncthreads();
    #pragma unroll 4
    for (int k = 0; k < 64; ++k) {
      float4 xv = *(const float4*)&Xt[k * 36 + rq * 4];
      float4 wv = *(const float4*)&Wl[k * 128 + col4];
      acc[0].x = fmaf(xv.x, wv.x, acc[0].x); acc[0].y = fmaf(xv.x, wv.y, acc[0].y);
      acc[0].z = fmaf(xv.x, wv.z, acc[0].z); acc[0].w = fmaf(xv.x, wv.w, acc[0].w);
      acc[1].x = fmaf(xv.y, wv.x, acc[1].x); acc[1].y = fmaf(xv.y, wv.y, acc[1].y);
      acc[1].z = fmaf(xv.y, wv.z, acc[1].z); acc[1].w = fmaf(xv.y, wv.w, acc[1].w);
      acc[2].x = fmaf(xv.z, wv.x, acc[2].x); acc[2].y = fmaf(xv.z, wv.y, acc[2].y);
      acc[2].z = fmaf(xv.z, wv.z, acc[2].z); acc[2].w = fmaf(xv.z, wv.w, acc[2].w);
      acc[3].x = fmaf(xv.w, wv.x, acc[3].x); acc[3].y = fmaf(xv.w, wv.y, acc[3].y);
      acc[3].z = fmaf(xv.w, wv.z, acc[3].z); acc[3].w = fmaf(xv.w, wv.w, acc[3].w);
    }
  }
  #pragma unroll
  for (int i = 0; i < 4; ++i) {
    long long row = row0 + rq * 4 + i;
    if (row < N) {
      ushort4 u;
      u.x = f2bf(acc[i].x); u.y = f2bf(acc[i].y);
      u.z = f2bf(acc[i].z); u.w = f2bf(acc[i].w);
      *(ushort4*)&XWb[row * 128 + col4] = u;
    }
  }
}

// ---------- 5. aggregate: H[i] = act(dinv[i]*sum(w_s*XW[s]) + dinv[i]^2*XW[i] + b) ----------
__global__ __launch_bounds__(256) void aggregate_k(const unsigned short* __restrict__ XWb,
    const int* __restrict__ rowptr, const int2* __restrict__ spk,
    const float* __restrict__ dinv, const float* __restrict__ bias,
    float* __restrict__ H, int N, int relu) {
  int wid = (blockIdx.x * 256 + threadIdx.x) >> 6;  // one wave per node
  if (wid >= N) return;
  int lane = threadIdx.x & 63;                      // lane owns features 2*lane, 2*lane+1
  int beg = rowptr[wid], end = rowptr[wid + 1];
  float di = dinv[wid];
  float ax = 0.f, ay = 0.f;
  int idx = beg;
  for (; idx + 1 < end; idx += 2) {
    int2 r0 = spk[idx], r1 = spk[idx + 1];
    float w0 = __int_as_float(r0.y), w1 = __int_as_float(r1.y);
    ushort2 u0 = *(const ushort2*)&XWb[(long long)r0.x * 128 + lane * 2];
    ushort2 u1 = *(const ushort2*)&XWb[(long long)r1.x * 128 + lane * 2];
    ax += w0 * bf2f(u0.x) + w1 * bf2f(u1.x);
    ay += w0 * bf2f(u0.y) + w1 * bf2f(u1.y);
  }
  if (idx < end) {
    int2 r0 = spk[idx];
    float w0 = __int_as_float(r0.y);
    ushort2 u0 = *(const ushort2*)&XWb[(long long)r0.x * 128 + lane * 2];
    ax += w0 * bf2f(u0.x);
    ay += w0 * bf2f(u0.y);
  }
  ushort2 su = *(const ushort2*)&XWb[(long long)wid * 128 + lane * 2];
  float ox = di * ax + di * di * bf2f(su.x);
  float oy = di * ay + di * di * bf2f(su.y);
  if (bias) { ox += bias[lane * 2]; oy += bias[lane * 2 + 1]; }
  if (relu) { ox = fmaxf(ox, 0.f); oy = fmaxf(oy, 0.f); }
  *(float2*)&H[(long long)wid * 128 + lane * 2] = make_float2(ox, oy);
}

// ---------- 6a. pool phase A: per-wave run-length partial sums + atomic flush ----------
__global__ __launch_bounds__(256) void pool_partial_k(const float* __restrict__ H,
    const int* __restrict__ batch, float* __restrict__ acc, int N,
    const int* __restrict__ flags) {
  const int i64 = flags[1];
  const int lane = threadIdx.x & 63;
  const int w = threadIdx.x >> 6;
  const int chunk = (N + gridDim.x - 1) / gridDim.x;
  const int bstart = blockIdx.x * chunk;
  const int bend = min(bstart + chunk, N);
  const int sub = (chunk + 3) / 4;
  const int s = bstart + w * sub;
  const int e = min(s + sub, bend);
  if (s >= e) return;
  float ax = 0.f, ay = 0.f;
  int curg = i64 ? batch[2 * s] : batch[s];
  for (int n = s; n < e; ++n) {
    int g = i64 ? batch[2 * n] : batch[n];   // sorted; uniform per wave
    if (g != curg) {
      atomicAdd(&acc[curg * 128 + lane * 2], ax);
      atomicAdd(&acc[curg * 128 + lane * 2 + 1], ay);
      ax = ay = 0.f; curg = g;
    }
    float2 v = *(const float2*)&H[(long long)n * 128 + lane * 2];
    ax += v.x; ay += v.y;
  }
  atomicAdd(&acc[curg * 128 + lane * 2], ax);
  atomicAdd(&acc[curg * 128 + lane * 2 + 1], ay);
}

// ---------- 6b. pool finalize: mean + b2 ----------
__global__ __launch_bounds__(128) void pool_final_k(const float* __restrict__ acc,
    const int* __restrict__ batch, const float* __restrict__ B2,
    float* __restrict__ out, int N, const int* __restrict__ flags) {
  __shared__ int sb[2];
  int g = blockIdx.x;
  int i64 = flags[1];
  if (threadIdx.x < 2) {
    int target = g + threadIdx.x;
    int lo = 0, hi = N;
    while (lo < hi) {
      int mid = (lo + hi) >> 1;
      int bv = i64 ? batch[2 * mid] : batch[mid];
      if (bv < target) lo = mid + 1; else hi = mid;
    }
    sb[threadIdx.x] = lo;
  }
  __syncthreads();
  int cnt = sb[1] - sb[0];
  int f = threadIdx.x;
  float res = 0.f;
  if (cnt > 0) res = acc[g * 128 + f] / (float)cnt + B2[f];
  out[g * 128 + f] = res;
}

extern "C" void kernel_launch(void* const* d_in, const int* in_sizes, int n_in,
                              void* d_out, int out_size, void* d_ws, size_t ws_size,
                              hipStream_t stream) {
  const int N = in_sizes[0] / 128;   // 50000
  const int E = in_sizes[1] / 2;     // 800000
  const int G = out_size / 128;      // 64
  const int NB = (N + 255) / 256;    // scan blocks

  const void* X  = d_in[0];                       // fp32 [N,128]
  const int*  EI = (const int*)d_in[1];           // int32 or int64 [2,E]
  const int*  BA = (const int*)d_in[2];           // int32 or int64 [N] sorted
  const void* W1 = d_in[3];
  const void* B1 = d_in[4];
  const void* W2 = d_in[5];
  const void* B2 = d_in[6];
  float* OUT = (float*)d_out;                     // fp32 [G,128]

  char* ws = (char*)d_ws;
  size_t o = 0;
  auto alloc = [&](size_t b) { size_t r = o; o += (b + 255) & ~(size_t)255; return r; };
  int*   flags  = (int*)(ws + alloc(256));
  float* w1f    = (float*)(ws + alloc(16384 * 4));
  float* w2f    = (float*)(ws + alloc(16384 * 4));
  float* b1f    = (float*)(ws + alloc(128 * 4));
  float* b2f    = (float*)(ws + alloc(128 * 4));
  float* acc    = (float*)(ws + alloc((size_t)G * 128 * 4));
  int*   deg    = (int*)(ws + alloc((size_t)N * 4));
  int*   bsum   = (int*)(ws + alloc((size_t)NB * 4));
  int*   boff   = (int*)(ws + alloc((size_t)NB * 4));
  int*   rowptr = (int*)(ws + alloc((size_t)(N + 1) * 4));
  int*   cursor = (int*)(ws + alloc((size_t)(N + 1) * 4));
  int2*  spk    = (int2*)(ws + alloc((size_t)E * 8));
  float* dinv   = (float*)(ws + alloc((size_t)N * 4));
  unsigned short* xwb = (unsigned short*)(ws + alloc((size_t)N * 128 * 2));  // bf16
  float* h1     = (float*)(ws + alloc((size_t)N * 128 * 4));
  float* h2     = h1;  // h1 dead after gemm2 stages it; safe alias

  const int TB = 256;
  // dtype probes + param converts (all params normalized to fp32)
  detect_all_k<<<6, 256, 0, stream>>>((const unsigned short*)X, EI,
                                      (const unsigned short*)W1, (const unsigned short*)W2,
                                      (const unsigned short*)B1, (const unsigned short*)B2,
                                      flags);
  cvt_f_k<<<64, 256, 0, stream>>>(W1, w1f, 16384, flags, 2);
  cvt_f_k<<<64, 256, 0, stream>>>(W2, w2f, 16384, flags, 3);
  cvt_f_k<<<1, 128, 0, stream>>>(B1, b1f, 128, flags, 4);
  cvt_f_k<<<1, 128, 0, stream>>>(B2, b2f, 128, flags, 5);

  // CSR build (shared by both layers)
  hipMemsetAsync(deg, 0, (size_t)N * 4, stream);
  hipMemsetAsync(acc, 0, (size_t)G * 128 * 4, stream);
  count_deg_k<<<(E + TB - 1) / TB, TB, 0, stream>>>(EI, deg, E, flags);
  scan1_k<<<NB, 256, 0, stream>>>(deg, bsum, N);
  scan2_k<<<1, 256, 0, stream>>>(bsum, boff, rowptr + N, NB);
  scan3_k<<<NB, 256, 0, stream>>>(deg, boff, rowptr, dinv, N);
  hipMemcpyAsync(cursor, rowptr, (size_t)N * 4, hipMemcpyDeviceToDevice, stream);
  scatter_k<<<(E + TB - 1) / TB, TB, 0, stream>>>(EI, cursor, spk, dinv, E, flags);

  dim3 ggrid((N + 31) / 32);
  dim3 agrid((N * 64 + 255) / 256);

  // layer 1
  gemm_k<<<ggrid, 256, 0, stream>>>(X, w1f, xwb, N, flags, 0);
  aggregate_k<<<agrid, 256, 0, stream>>>(xwb, rowptr, spk, dinv, b1f, h1, N, 1);
  // layer 2
  gemm_k<<<ggrid, 256, 0, stream>>>(h1, w2f, xwb, N, flags, 1);
  aggregate_k<<<agrid, 256, 0, stream>>>(xwb, rowptr, spk, dinv, (const float*)nullptr, h2, N, 0);
  // pool (two-phase)
  pool_partial_k<<<512, 256, 0, stream>>>(h2, BA, acc, N, flags);
  pool_final_k<<<G, 128, 0, stream>>>(acc, BA, b2f, OUT, N, flags);
}

// Round 6
// 356.870 us; speedup vs baseline: 1.9571x; 1.1011x over previous
//
#include <hip/hip_runtime.h>
#include <hip/hip_bf16.h>

// ---------- bf16 helpers (OCP bf16 = fp32 upper 16 bits) ----------
__device__ __forceinline__ float bf2f(unsigned short u) {
  union { unsigned int i; float f; } v; v.i = ((unsigned int)u) << 16; return v.f;
}
__device__ __forceinline__ unsigned short f2bf(float f) {
  union { float f; unsigned int i; } v; v.f = f;
  unsigned int x = v.i;
  return (unsigned short)((x + 0x7fffu + ((x >> 16) & 1u)) >> 16);  // RNE
}

// ---------- 0. per-tensor runtime dtype detection ----------
// flags[0]=x_fp32  flags[1]=int64  flags[2]=w1_fp32  flags[3]=w2_fp32
// flags[4]=b1_fp32 flags[5]=b2_fp32
__global__ __launch_bounds__(256) void detect_all_k(
    const unsigned short* __restrict__ xu,  const int* __restrict__ ei,
    const unsigned short* __restrict__ w1u, const unsigned short* __restrict__ w2u,
    const unsigned short* __restrict__ b1u, const unsigned short* __restrict__ b2u,
    int* __restrict__ flags) {
  __shared__ int s_cnt;
  if (threadIdx.x == 0) s_cnt = 0;
  __syncthreads();
  const int b = blockIdx.x;
  int cnt = 0;
  if (b == 1) {  // int width: high words of int64 positives are all zero
    for (int i = threadIdx.x; i < 4096; i += 256)
      if (ei[2 * i + 1] == 0) cnt++;
    atomicAdd(&s_cnt, cnt);
    __syncthreads();
    if (threadIdx.x == 0) flags[1] = (s_cnt > 2048) ? 1 : 0;
    return;
  }
  const unsigned short* p; int n; int fi;
  if (b == 0)      { p = xu;  n = 16384; fi = 0; }
  else if (b == 2) { p = w1u; n = 16384; fi = 2; }
  else if (b == 3) { p = w2u; n = 16384; fi = 3; }
  else if (b == 4) { p = b1u; n = 128;   fi = 4; }
  else             { p = b2u; n = 128;   fi = 5; }
  for (int i = threadIdx.x; i < n; i += 256) {
    int e = (p[i] >> 7) & 0xFF;
    if (e < 96 || e > 159) cnt++;   // wild bf16 exponent => fp32 data
  }
  atomicAdd(&s_cnt, cnt);
  __syncthreads();
  if (threadIdx.x == 0) flags[fi] = (s_cnt * 8 > n) ? 1 : 0;
}

// ---------- merged param convert: anything -> fp32 ----------
// blocks 0..63: W1, 64..127: W2, 128: b1 (tid<128) + b2 (tid>=128)
__global__ __launch_bounds__(256) void cvt_all_k(
    const void* __restrict__ W1, const void* __restrict__ W2,
    const void* __restrict__ B1, const void* __restrict__ B2,
    float* __restrict__ w1f, float* __restrict__ w2f,
    float* __restrict__ b1f, float* __restrict__ b2f,
    const int* __restrict__ flags) {
  int b = blockIdx.x;
  if (b < 64) {
    int i = b * 256 + threadIdx.x;
    w1f[i] = flags[2] ? ((const float*)W1)[i] : bf2f(((const unsigned short*)W1)[i]);
  } else if (b < 128) {
    int i = (b - 64) * 256 + threadIdx.x;
    w2f[i] = flags[3] ? ((const float*)W2)[i] : bf2f(((const unsigned short*)W2)[i]);
  } else {
    if (threadIdx.x < 128)
      b1f[threadIdx.x] = flags[4] ? ((const float*)B1)[threadIdx.x]
                                  : bf2f(((const unsigned short*)B1)[threadIdx.x]);
    else {
      int i = threadIdx.x - 128;
      b2f[i] = flags[5] ? ((const float*)B2)[i] : bf2f(((const unsigned short*)B2)[i]);
    }
  }
}

// ---------- 1. degree count (in-degree at dst) ----------
__global__ void count_deg_k(const int* __restrict__ ei, int* __restrict__ deg, int E,
                            const int* __restrict__ flags) {
  int e = blockIdx.x * blockDim.x + threadIdx.x;
  if (e >= E) return;
  int d = flags[1] ? ei[2 * (E + e)] : ei[E + e];
  atomicAdd(&deg[d], 1);
}

// ---------- 2. hierarchical exclusive scan (3 tiny kernels) ----------
__global__ __launch_bounds__(256) void scan1_k(const int* __restrict__ deg,
                                               int* __restrict__ bsum, int N) {
  __shared__ int red[4];
  int i = blockIdx.x * 256 + threadIdx.x;
  int v = (i < N) ? deg[i] : 0;
  int lane = threadIdx.x & 63, w = threadIdx.x >> 6;
  #pragma unroll
  for (int off = 32; off > 0; off >>= 1) v += __shfl_down(v, off, 64);
  if (lane == 0) red[w] = v;
  __syncthreads();
  if (threadIdx.x == 0) bsum[blockIdx.x] = red[0] + red[1] + red[2] + red[3];
}
__global__ __launch_bounds__(256) void scan2_k(const int* __restrict__ bsum,
                                               int* __restrict__ boff,
                                               int* __restrict__ rowptrN, int nb) {
  __shared__ int ws[4];
  const int tid = threadIdx.x, lane = tid & 63, w = tid >> 6;
  int carry = 0;
  for (int base = 0; base < nb; base += 256) {
    int i = base + tid;
    int v = (i < nb) ? bsum[i] : 0;
    int inc = v;
    #pragma unroll
    for (int off = 1; off < 64; off <<= 1) {
      int n = __shfl_up(inc, off, 64);
      if (lane >= off) inc += n;
    }
    if (lane == 63) ws[w] = inc;
    __syncthreads();
    int woff = 0, tot = 0;
    #pragma unroll
    for (int k = 0; k < 4; ++k) { int s = ws[k]; if (k < w) woff += s; tot += s; }
    if (i < nb) boff[i] = carry + woff + inc - v;
    carry += tot;
    __syncthreads();
  }
  if (tid == 0) *rowptrN = carry;
}
__global__ __launch_bounds__(256) void scan3_k(const int* __restrict__ deg,
                                               const int* __restrict__ boff,
                                               int* __restrict__ rowptr,
                                               float* __restrict__ dinv, int N) {
  __shared__ int ws[4];
  int i = blockIdx.x * 256 + threadIdx.x;
  int lane = threadIdx.x & 63, w = threadIdx.x >> 6;
  int v = (i < N) ? deg[i] : 0;
  int inc = v;
  #pragma unroll
  for (int off = 1; off < 64; off <<= 1) {
    int n = __shfl_up(inc, off, 64);
    if (lane >= off) inc += n;
  }
  if (lane == 63) ws[w] = inc;
  __syncthreads();
  int woff = 0;
  #pragma unroll
  for (int k = 0; k < 4; ++k) if (k < w) woff += ws[k];
  if (i < N) {
    rowptr[i] = boff[blockIdx.x] + woff + inc - v;
    dinv[i] = rsqrtf((float)(v + 1));  // +1 self-loop
  }
}

// ---------- 3. counting-sort edges by dst; payload = {src, dinv[src]} ----------
__global__ void scatter_k(const int* __restrict__ ei, int* __restrict__ cursor,
                          int2* __restrict__ spk, const float* __restrict__ dinv,
                          int E, const int* __restrict__ flags) {
  int e = blockIdx.x * blockDim.x + threadIdx.x;
  if (e >= E) return;
  int s, d;
  if (flags[1]) { s = ei[2 * e]; d = ei[2 * (E + e)]; }
  else          { s = ei[e];     d = ei[E + e]; }
  int pos = atomicAdd(&cursor[d], 1);
  int2 rec; rec.x = s; rec.y = __float_as_int(dinv[s]);
  spk[pos] = rec;
}

// ---------- 4. GEMM: XWb[N,128](bf16) = X[N,128](fp32) @ W[128,128](fp32) ----------
__global__ __launch_bounds__(256) void gemm_k(const void* __restrict__ X,
                                              const float* __restrict__ Wf,
                                              unsigned short* __restrict__ XWb, int N,
                                              const int* __restrict__ flags, int xmode) {
  __shared__ __align__(16) float Wl[64 * 128];   // 32 KB (one 64-k slab, fp32)
  __shared__ __align__(16) float Xt[64 * 36];    // 9.2 KB transposed [k'][r], pad 36
  const int tid = threadIdx.x;
  const int xf32 = xmode ? 1 : flags[0];
  const long long row0 = (long long)blockIdx.x * 32;
  const int col4 = (tid & 31) * 4;
  const int rq = tid >> 5;
  float4 acc[4];
  #pragma unroll
  for (int i = 0; i < 4; ++i) acc[i] = make_float4(0.f, 0.f, 0.f, 0.f);

  for (int p = 0; p < 2; ++p) {
    if (p) __syncthreads();
    for (int t = tid; t < 2048; t += 256) {
      int kk = t >> 5, c4 = (t & 31) * 4;
      *(float4*)&Wl[kk * 128 + c4] = *(const float4*)&Wf[(p * 64 + kk) * 128 + c4];
    }
    for (int t = tid; t < 2048; t += 256) {
      int r = t >> 6, kk = t & 63;
      long long row = row0 + r;
      float v = 0.f;
      if (row < N) {
        long long gi = row * 128 + p * 64 + kk;
        v = xf32 ? ((const float*)X)[gi] : bf2f(((const unsigned short*)X)[gi]);
      }
      Xt[kk * 36 + r] = v;
    }
    __syncthreads();
    #pragma unroll 4
    for (int k = 0; k < 64; ++k) {
      float4 xv = *(const float4*)&Xt[k * 36 + rq * 4];
      float4 wv = *(const float4*)&Wl[k * 128 + col4];
      acc[0].x = fmaf(xv.x, wv.x, acc[0].x); acc[0].y = fmaf(xv.x, wv.y, acc[0].y);
      acc[0].z = fmaf(xv.x, wv.z, acc[0].z); acc[0].w = fmaf(xv.x, wv.w, acc[0].w);
      acc[1].x = fmaf(xv.y, wv.x, acc[1].x); acc[1].y = fmaf(xv.y, wv.y, acc[1].y);
      acc[1].z = fmaf(xv.y, wv.z, acc[1].z); acc[1].w = fmaf(xv.y, wv.w, acc[1].w);
      acc[2].x = fmaf(xv.z, wv.x, acc[2].x); acc[2].y = fmaf(xv.z, wv.y, acc[2].y);
      acc[2].z = fmaf(xv.z, wv.z, acc[2].z); acc[2].w = fmaf(xv.z, wv.w, acc[2].w);
      acc[3].x = fmaf(xv.w, wv.x, acc[3].x); acc[3].y = fmaf(xv.w, wv.y, acc[3].y);
      acc[3].z = fmaf(xv.w, wv.z, acc[3].z); acc[3].w = fmaf(xv.w, wv.w, acc[3].w);
    }
  }
  #pragma unroll
  for (int i = 0; i < 4; ++i) {
    long long row = row0 + rq * 4 + i;
    if (row < N) {
      ushort4 u;
      u.x = f2bf(acc[i].x); u.y = f2bf(acc[i].y);
      u.z = f2bf(acc[i].z); u.w = f2bf(acc[i].w);
      *(ushort4*)&XWb[row * 128 + col4] = u;
    }
  }
}

// ---------- 5. aggregate: H[i] = act(dinv[i]*sum(w_s*XW[s]) + dinv[i]^2*XW[i] + b) ----------
// One wave per node. Lane owns 4 features; half-waves process 2 edges per
// gather instruction (32 lanes x ushort4 = one 256B row). 4-edge unroll ->
// 2 gather insts (4 edges) in flight per wave. Cross-half shfl_xor reduce.
__global__ __launch_bounds__(256) void aggregate_k(const unsigned short* __restrict__ XWb,
    const int* __restrict__ rowptr, const int2* __restrict__ spk,
    const float* __restrict__ dinv, const float* __restrict__ bias,
    float* __restrict__ H, int N, int relu) {
  int wid = (blockIdx.x * 256 + threadIdx.x) >> 6;  // one wave per node
  if (wid >= N) return;
  const int lane = threadIdx.x & 63;
  const int half = lane >> 5;        // 0: even edge of pair, 1: odd edge
  const int fl = (lane & 31) * 4;    // feature base (4 features per lane)
  const int beg = rowptr[wid], end = rowptr[wid + 1];
  const float di = dinv[wid];
  float a0 = 0.f, a1 = 0.f, a2 = 0.f, a3 = 0.f;
  int idx = beg;
  for (; idx + 4 <= end; idx += 4) {
    int2 rA = spk[idx + half];
    int2 rB = spk[idx + 2 + half];
    float wA = __int_as_float(rA.y);
    float wB = __int_as_float(rB.y);
    ushort4 uA = *(const ushort4*)&XWb[(long long)rA.x * 128 + fl];
    ushort4 uB = *(const ushort4*)&XWb[(long long)rB.x * 128 + fl];
    a0 += wA * bf2f(uA.x) + wB * bf2f(uB.x);
    a1 += wA * bf2f(uA.y) + wB * bf2f(uB.y);
    a2 += wA * bf2f(uA.z) + wB * bf2f(uB.z);
    a3 += wA * bf2f(uA.w) + wB * bf2f(uB.w);
  }
  if (idx < end) {                               // remainder 1..3 edges
    int iA = idx + half;
    int2 rA = spk[min(iA, end - 1)];
    float wA = (iA < end) ? __int_as_float(rA.y) : 0.f;
    ushort4 uA = *(const ushort4*)&XWb[(long long)rA.x * 128 + fl];
    a0 += wA * bf2f(uA.x); a1 += wA * bf2f(uA.y);
    a2 += wA * bf2f(uA.z); a3 += wA * bf2f(uA.w);
    if (idx + 2 < end) {
      int iB = idx + 2 + half;
      int2 rB = spk[min(iB, end - 1)];
      float wB = (iB < end) ? __int_as_float(rB.y) : 0.f;
      ushort4 uB = *(const ushort4*)&XWb[(long long)rB.x * 128 + fl];
      a0 += wB * bf2f(uB.x); a1 += wB * bf2f(uB.y);
      a2 += wB * bf2f(uB.z); a3 += wB * bf2f(uB.w);
    }
  }
  a0 += __shfl_xor(a0, 32, 64);
  a1 += __shfl_xor(a1, 32, 64);
  a2 += __shfl_xor(a2, 32, 64);
  a3 += __shfl_xor(a3, 32, 64);
  if (half == 0) {
    ushort4 su = *(const ushort4*)&XWb[(long long)wid * 128 + fl];
    float d2 = di * di;
    float o0 = di * a0 + d2 * bf2f(su.x);
    float o1 = di * a1 + d2 * bf2f(su.y);
    float o2 = di * a2 + d2 * bf2f(su.z);
    float o3 = di * a3 + d2 * bf2f(su.w);
    if (bias) {
      float4 bv = *(const float4*)&bias[fl];
      o0 += bv.x; o1 += bv.y; o2 += bv.z; o3 += bv.w;
    }
    if (relu) {
      o0 = fmaxf(o0, 0.f); o1 = fmaxf(o1, 0.f);
      o2 = fmaxf(o2, 0.f); o3 = fmaxf(o3, 0.f);
    }
    *(float4*)&H[(long long)wid * 128 + fl] = make_float4(o0, o1, o2, o3);
  }
}

// ---------- 6a. pool phase A: per-wave run-length partial sums + atomic flush ----------
__global__ __launch_bounds__(256) void pool_partial_k(const float* __restrict__ H,
    const int* __restrict__ batch, float* __restrict__ acc, int N,
    const int* __restrict__ flags) {
  const int i64 = flags[1];
  const int lane = threadIdx.x & 63;
  const int w = threadIdx.x >> 6;
  const int chunk = (N + gridDim.x - 1) / gridDim.x;
  const int bstart = blockIdx.x * chunk;
  const int bend = min(bstart + chunk, N);
  const int sub = (chunk + 3) / 4;
  const int s = bstart + w * sub;
  const int e = min(s + sub, bend);
  if (s >= e) return;
  float ax = 0.f, ay = 0.f;
  int curg = i64 ? batch[2 * s] : batch[s];
  for (int n = s; n < e; ++n) {
    int g = i64 ? batch[2 * n] : batch[n];   // sorted; uniform per wave
    if (g != curg) {
      atomicAdd(&acc[curg * 128 + lane * 2], ax);
      atomicAdd(&acc[curg * 128 + lane * 2 + 1], ay);
      ax = ay = 0.f; curg = g;
    }
    float2 v = *(const float2*)&H[(long long)n * 128 + lane * 2];
    ax += v.x; ay += v.y;
  }
  atomicAdd(&acc[curg * 128 + lane * 2], ax);
  atomicAdd(&acc[curg * 128 + lane * 2 + 1], ay);
}

// ---------- 6b. pool finalize: mean + b2 ----------
__global__ __launch_bounds__(128) void pool_final_k(const float* __restrict__ acc,
    const int* __restrict__ batch, const float* __restrict__ B2,
    float* __restrict__ out, int N, const int* __restrict__ flags) {
  __shared__ int sb[2];
  int g = blockIdx.x;
  int i64 = flags[1];
  if (threadIdx.x < 2) {
    int target = g + threadIdx.x;
    int lo = 0, hi = N;
    while (lo < hi) {
      int mid = (lo + hi) >> 1;
      int bv = i64 ? batch[2 * mid] : batch[mid];
      if (bv < target) lo = mid + 1; else hi = mid;
    }
    sb[threadIdx.x] = lo;
  }
  __syncthreads();
  int cnt = sb[1] - sb[0];
  int f = threadIdx.x;
  float res = 0.f;
  if (cnt > 0) res = acc[g * 128 + f] / (float)cnt + B2[f];
  out[g * 128 + f] = res;
}

extern "C" void kernel_launch(void* const* d_in, const int* in_sizes, int n_in,
                              void* d_out, int out_size, void* d_ws, size_t ws_size,
                              hipStream_t stream) {
  const int N = in_sizes[0] / 128;   // 50000
  const int E = in_sizes[1] / 2;     // 800000
  const int G = out_size / 128;      // 64
  const int NB = (N + 255) / 256;    // scan blocks

  const void* X  = d_in[0];                       // fp32 [N,128]
  const int*  EI = (const int*)d_in[1];           // int32 or int64 [2,E]
  const int*  BA = (const int*)d_in[2];           // int32 or int64 [N] sorted
  const void* W1 = d_in[3];
  const void* B1 = d_in[4];
  const void* W2 = d_in[5];
  const void* B2 = d_in[6];
  float* OUT = (float*)d_out;                     // fp32 [G,128]

  char* ws = (char*)d_ws;
  size_t o = 0;
  auto alloc = [&](size_t b) { size_t r = o; o += (b + 255) & ~(size_t)255; return r; };
  int*   flags  = (int*)(ws + alloc(256));
  float* w1f    = (float*)(ws + alloc(16384 * 4));
  float* w2f    = (float*)(ws + alloc(16384 * 4));
  float* b1f    = (float*)(ws + alloc(128 * 4));
  float* b2f    = (float*)(ws + alloc(128 * 4));
  float* acc    = (float*)(ws + alloc((size_t)G * 128 * 4));
  int*   deg    = (int*)(ws + alloc((size_t)N * 4));
  int*   bsum   = (int*)(ws + alloc((size_t)NB * 4));
  int*   boff   = (int*)(ws + alloc((size_t)NB * 4));
  int*   rowptr = (int*)(ws + alloc((size_t)(N + 1) * 4));
  int*   cursor = (int*)(ws + alloc((size_t)(N + 1) * 4));
  int2*  spk    = (int2*)(ws + alloc((size_t)E * 8));
  float* dinv   = (float*)(ws + alloc((size_t)N * 4));
  unsigned short* xwb = (unsigned short*)(ws + alloc((size_t)N * 128 * 2));  // bf16
  float* h1     = (float*)(ws + alloc((size_t)N * 128 * 4));
  float* h2     = h1;  // h1 dead after gemm2 stages it; safe alias

  const int TB = 256;
  // dtype probes + merged param convert (all params normalized to fp32)
  detect_all_k<<<6, 256, 0, stream>>>((const unsigned short*)X, EI,
                                      (const unsigned short*)W1, (const unsigned short*)W2,
                                      (const unsigned short*)B1, (const unsigned short*)B2,
                                      flags);
  cvt_all_k<<<129, 256, 0, stream>>>(W1, W2, B1, B2, w1f, w2f, b1f, b2f, flags);

  // CSR build (shared by both layers)
  hipMemsetAsync(deg, 0, (size_t)N * 4, stream);
  hipMemsetAsync(acc, 0, (size_t)G * 128 * 4, stream);
  count_deg_k<<<(E + TB - 1) / TB, TB, 0, stream>>>(EI, deg, E, flags);
  scan1_k<<<NB, 256, 0, stream>>>(deg, bsum, N);
  scan2_k<<<1, 256, 0, stream>>>(bsum, boff, rowptr + N, NB);
  scan3_k<<<NB, 256, 0, stream>>>(deg, boff, rowptr, dinv, N);
  hipMemcpyAsync(cursor, rowptr, (size_t)N * 4, hipMemcpyDeviceToDevice, stream);
  scatter_k<<<(E + TB - 1) / TB, TB, 0, stream>>>(EI, cursor, spk, dinv, E, flags);

  dim3 ggrid((N + 31) / 32);
  dim3 agrid((N * 64 + 255) / 256);

  // layer 1
  gemm_k<<<ggrid, 256, 0, stream>>>(X, w1f, xwb, N, flags, 0);
  aggregate_k<<<agrid, 256, 0, stream>>>(xwb, rowptr, spk, dinv, b1f, h1, N, 1);
  // layer 2
  gemm_k<<<ggrid, 256, 0, stream>>>(h1, w2f, xwb, N, flags, 1);
  aggregate_k<<<agrid, 256, 0, stream>>>(xwb, rowptr, spk, dinv, (const float*)nullptr, h2, N, 0);
  // pool (two-phase)
  pool_partial_k<<<512, 256, 0, stream>>>(h2, BA, acc, N, flags);
  pool_final_k<<<G, 128, 0, stream>>>(acc, BA, b2f, OUT, N, flags);
}

// Round 7
// 331.262 us; speedup vs baseline: 2.1084x; 1.0773x over previous
//
#include <hip/hip_runtime.h>
#include <hip/hip_bf16.h>

#define SPAN_SHIFT 8   // dst-bucket span = 256 nodes (NBKT = ceil(N/256) <= 256 for N<=65536)

// ---------- bf16 helpers (OCP bf16 = fp32 upper 16 bits) ----------
__device__ __forceinline__ float bf2f(unsigned short u) {
  union { unsigned int i; float f; } v; v.i = ((unsigned int)u) << 16; return v.f;
}
__device__ __forceinline__ unsigned short f2bf(float f) {
  union { float f; unsigned int i; } v; v.f = f;
  unsigned int x = v.i;
  return (unsigned short)((x + 0x7fffu + ((x >> 16) & 1u)) >> 16);  // RNE
}

// ---------- 0. per-tensor runtime dtype detection ----------
// flags[0]=x_fp32  flags[1]=int64  flags[2]=w1_fp32  flags[3]=w2_fp32
// flags[4]=b1_fp32 flags[5]=b2_fp32
__global__ __launch_bounds__(256) void detect_all_k(
    const unsigned short* __restrict__ xu,  const int* __restrict__ ei,
    const unsigned short* __restrict__ w1u, const unsigned short* __restrict__ w2u,
    const unsigned short* __restrict__ b1u, const unsigned short* __restrict__ b2u,
    int* __restrict__ flags) {
  __shared__ int s_cnt;
  if (threadIdx.x == 0) s_cnt = 0;
  __syncthreads();
  const int b = blockIdx.x;
  int cnt = 0;
  if (b == 1) {  // int width: high words of int64 positives are all zero
    for (int i = threadIdx.x; i < 4096; i += 256)
      if (ei[2 * i + 1] == 0) cnt++;
    atomicAdd(&s_cnt, cnt);
    __syncthreads();
    if (threadIdx.x == 0) flags[1] = (s_cnt > 2048) ? 1 : 0;
    return;
  }
  const unsigned short* p; int n; int fi;
  if (b == 0)      { p = xu;  n = 16384; fi = 0; }
  else if (b == 2) { p = w1u; n = 16384; fi = 2; }
  else if (b == 3) { p = w2u; n = 16384; fi = 3; }
  else if (b == 4) { p = b1u; n = 128;   fi = 4; }
  else             { p = b2u; n = 128;   fi = 5; }
  for (int i = threadIdx.x; i < n; i += 256) {
    int e = (p[i] >> 7) & 0xFF;
    if (e < 96 || e > 159) cnt++;   // wild bf16 exponent => fp32 data
  }
  atomicAdd(&s_cnt, cnt);
  __syncthreads();
  if (threadIdx.x == 0) flags[fi] = (s_cnt * 8 > n) ? 1 : 0;
}

// ---------- merged param convert: anything -> fp32 ----------
__global__ __launch_bounds__(256) void cvt_all_k(
    const void* __restrict__ W1, const void* __restrict__ W2,
    const void* __restrict__ B1, const void* __restrict__ B2,
    float* __restrict__ w1f, float* __restrict__ w2f,
    float* __restrict__ b1f, float* __restrict__ b2f,
    const int* __restrict__ flags) {
  int b = blockIdx.x;
  if (b < 64) {
    int i = b * 256 + threadIdx.x;
    w1f[i] = flags[2] ? ((const float*)W1)[i] : bf2f(((const unsigned short*)W1)[i]);
  } else if (b < 128) {
    int i = (b - 64) * 256 + threadIdx.x;
    w2f[i] = flags[3] ? ((const float*)W2)[i] : bf2f(((const unsigned short*)W2)[i]);
  } else {
    if (threadIdx.x < 128)
      b1f[threadIdx.x] = flags[4] ? ((const float*)B1)[threadIdx.x]
                                  : bf2f(((const unsigned short*)B1)[threadIdx.x]);
    else {
      int i = threadIdx.x - 128;
      b2f[i] = flags[5] ? ((const float*)B2)[i] : bf2f(((const unsigned short*)B2)[i]);
    }
  }
}

// ---------- 1. degree count (in-degree at dst) ----------
__global__ void count_deg_k(const int* __restrict__ ei, int* __restrict__ deg, int E,
                            const int* __restrict__ flags) {
  int e = blockIdx.x * blockDim.x + threadIdx.x;
  if (e >= E) return;
  int d = flags[1] ? ei[2 * (E + e)] : ei[E + e];
  atomicAdd(&deg[d], 1);
}

// ---------- 2. hierarchical exclusive scan (3 tiny kernels) ----------
__global__ __launch_bounds__(256) void scan1_k(const int* __restrict__ deg,
                                               int* __restrict__ bsum, int N) {
  __shared__ int red[4];
  int i = blockIdx.x * 256 + threadIdx.x;
  int v = (i < N) ? deg[i] : 0;
  int lane = threadIdx.x & 63, w = threadIdx.x >> 6;
  #pragma unroll
  for (int off = 32; off > 0; off >>= 1) v += __shfl_down(v, off, 64);
  if (lane == 0) red[w] = v;
  __syncthreads();
  if (threadIdx.x == 0) bsum[blockIdx.x] = red[0] + red[1] + red[2] + red[3];
}
__global__ __launch_bounds__(256) void scan2_k(const int* __restrict__ bsum,
                                               int* __restrict__ boff,
                                               int* __restrict__ rowptrN, int nb) {
  __shared__ int ws[4];
  const int tid = threadIdx.x, lane = tid & 63, w = tid >> 6;
  int carry = 0;
  for (int base = 0; base < nb; base += 256) {
    int i = base + tid;
    int v = (i < nb) ? bsum[i] : 0;
    int inc = v;
    #pragma unroll
    for (int off = 1; off < 64; off <<= 1) {
      int n = __shfl_up(inc, off, 64);
      if (lane >= off) inc += n;
    }
    if (lane == 63) ws[w] = inc;
    __syncthreads();
    int woff = 0, tot = 0;
    #pragma unroll
    for (int k = 0; k < 4; ++k) { int s = ws[k]; if (k < w) woff += s; tot += s; }
    if (i < nb) boff[i] = carry + woff + inc - v;
    carry += tot;
    __syncthreads();
  }
  if (tid == 0) *rowptrN = carry;
}
__global__ __launch_bounds__(256) void scan3_k(const int* __restrict__ deg,
                                               const int* __restrict__ boff,
                                               int* __restrict__ rowptr,
                                               float* __restrict__ dinv, int N) {
  __shared__ int ws[4];
  int i = blockIdx.x * 256 + threadIdx.x;
  int lane = threadIdx.x & 63, w = threadIdx.x >> 6;
  int v = (i < N) ? deg[i] : 0;
  int inc = v;
  #pragma unroll
  for (int off = 1; off < 64; off <<= 1) {
    int n = __shfl_up(inc, off, 64);
    if (lane >= off) inc += n;
  }
  if (lane == 63) ws[w] = inc;
  __syncthreads();
  int woff = 0;
  #pragma unroll
  for (int k = 0; k < 4; ++k) if (k < w) woff += ws[k];
  if (i < N) {
    rowptr[i] = boff[blockIdx.x] + woff + inc - v;
    dinv[i] = rsqrtf((float)(v + 1));  // +1 self-loop
  }
}

// ---------- 3a. bucket cursor init: bcur[b] = rowptr[b*256] ----------
__global__ void init_bcur_k(const int* __restrict__ rowptr, int* __restrict__ bcur,
                            int N, int NBKT) {
  int t = blockIdx.x * blockDim.x + threadIdx.x;
  if (t < NBKT) bcur[t] = rowptr[min(t << SPAN_SHIFT, N)];
}

// ---------- 3b. pass A: LDS radix-partition edges into dst-buckets ----------
// Block stages 4096 edges in LDS grouped by bucket, reserves contiguous global
// chunks (1 atomic per bucket), writes coalesced chunk runs -> full-line writes.
__global__ __launch_bounds__(256) void scatterA_k(const int* __restrict__ ei,
    int* __restrict__ bcur, int2* __restrict__ tmp, int E,
    const int* __restrict__ flags, int NBKT) {
  __shared__ int2 stage[4096];                 // 32 KB
  __shared__ int hist[256], off[256], cnt2[256], gbase[256];
  __shared__ int wsum[4];
  const int tid = threadIdx.x;
  hist[tid] = 0; cnt2[tid] = 0;
  __syncthreads();
  const int base = blockIdx.x * 4096;
  const int i64 = flags[1];
  int rs[16], rd[16];
  #pragma unroll
  for (int j = 0; j < 16; ++j) {
    int e = base + j * 256 + tid;
    if (e < E) {
      int s, d;
      if (i64) { s = ei[2 * e]; d = ei[2 * (E + e)]; }
      else     { s = ei[e];     d = ei[E + e]; }
      rs[j] = s; rd[j] = d;
      atomicAdd(&hist[d >> SPAN_SHIFT], 1);
    } else rd[j] = -1;
  }
  __syncthreads();
  // exclusive scan of hist[0..255] -> off
  {
    int lane = tid & 63, w = tid >> 6;
    int v = hist[tid], inc = v;
    #pragma unroll
    for (int o = 1; o < 64; o <<= 1) { int n = __shfl_up(inc, o, 64); if (lane >= o) inc += n; }
    if (lane == 63) wsum[w] = inc;
    __syncthreads();
    int pre = 0;
    #pragma unroll
    for (int k = 0; k < 4; ++k) if (k < w) pre += wsum[k];
    off[tid] = pre + inc - v;
  }
  __syncthreads();
  // rank within bucket + stage into LDS, grouped by bucket
  #pragma unroll
  for (int j = 0; j < 16; ++j) {
    if (rd[j] >= 0) {
      int b = rd[j] >> SPAN_SHIFT;
      int r = atomicAdd(&cnt2[b], 1);
      int2 rec; rec.x = rs[j]; rec.y = rd[j];
      stage[off[b] + r] = rec;
    }
  }
  // reserve global chunk per bucket
  if (tid < NBKT && hist[tid] > 0) gbase[tid] = atomicAdd(&bcur[tid], hist[tid]);
  __syncthreads();
  const int total = off[255] + hist[255];
  for (int i = tid; i < total; i += 256) {          // consecutive i -> consecutive dst
    int2 rec = stage[i];
    int b = rec.y >> SPAN_SHIFT;
    tmp[gbase[b] + (i - off[b])] = rec;
  }
}

// ---------- 3c. pass B: one block per bucket, LDS cursors -> final CSR ----------
__global__ __launch_bounds__(256) void scatterB_k(const int2* __restrict__ tmp,
    const int* __restrict__ rowptr, const float* __restrict__ dinv,
    int2* __restrict__ spk, int N) {
  __shared__ int cur[256];
  const int tid = threadIdx.x;
  const int n0 = blockIdx.x << SPAN_SHIFT;
  const int n1 = min(n0 + 256, N);
  if (n0 + tid < n1) cur[tid] = rowptr[n0 + tid];
  __syncthreads();
  const int e0 = rowptr[n0], e1 = rowptr[n1];
  for (int i = e0 + tid; i < e1; i += 256) {
    int2 rec = tmp[i];
    int pos = atomicAdd(&cur[rec.y - n0], 1);
    int2 out; out.x = rec.x; out.y = __float_as_int(dinv[rec.x]);
    spk[pos] = out;   // all writes to this 32KB window come from this block -> L2 merge
  }
}

// ---------- 4. GEMM: XWb[N,128](bf16) = X[N,128](fp32) @ W[128,128](fp32) ----------
// 64 rows/block; 8 rows x 4 cols per thread (1.33 FLOP per LDS byte); 2 k-phases.
__global__ __launch_bounds__(256) void gemm_k(const void* __restrict__ X,
                                              const float* __restrict__ Wf,
                                              unsigned short* __restrict__ XWb, int N,
                                              const int* __restrict__ flags, int xmode) {
  __shared__ __align__(16) float Wl[64 * 128];   // 32 KB (one 64-k slab, fp32)
  __shared__ __align__(16) float Xt[64 * 68];    // 17.4 KB transposed [k'][r], pad 68
  const int tid = threadIdx.x;
  const int xf32 = xmode ? 1 : flags[0];
  const long long row0 = (long long)blockIdx.x * 64;
  const int col4 = (tid & 31) * 4;   // 4 consecutive output cols
  const int rg = tid >> 5;           // row-group: rows rg*8 .. rg*8+7
  float4 acc[8];
  #pragma unroll
  for (int i = 0; i < 8; ++i) acc[i] = make_float4(0.f, 0.f, 0.f, 0.f);

  for (int p = 0; p < 2; ++p) {
    if (p) __syncthreads();
    // stage W slab (coalesced float4)
    for (int t = tid; t < 2048; t += 256) {
      int kk = t >> 5, c4 = (t & 31) * 4;
      *(float4*)&Wl[kk * 128 + c4] = *(const float4*)&Wf[(p * 64 + kk) * 128 + c4];
    }
    // stage X tile transposed: 64 rows x 64 k'
    for (int t = tid; t < 1024; t += 256) {
      int r = t >> 4, kk = (t & 15) * 4;
      long long row = row0 + r;
      float4 v = make_float4(0.f, 0.f, 0.f, 0.f);
      if (row < N) {
        long long gi = row * 128 + p * 64 + kk;
        if (xf32) v = *(const float4*)&((const float*)X)[gi];
        else {
          ushort4 u = *(const ushort4*)&((const unsigned short*)X)[gi];
          v = make_float4(bf2f(u.x), bf2f(u.y), bf2f(u.z), bf2f(u.w));
        }
      }
      Xt[(kk + 0) * 68 + r] = v.x;
      Xt[(kk + 1) * 68 + r] = v.y;
      Xt[(kk + 2) * 68 + r] = v.z;
      Xt[(kk + 3) * 68 + r] = v.w;
    }
    __syncthreads();
    #pragma unroll 2
    for (int k = 0; k < 64; ++k) {
      float4 wv = *(const float4*)&Wl[k * 128 + col4];
      float4 x0 = *(const float4*)&Xt[k * 68 + rg * 8];
      float4 x1 = *(const float4*)&Xt[k * 68 + rg * 8 + 4];
      acc[0].x = fmaf(x0.x, wv.x, acc[0].x); acc[0].y = fmaf(x0.x, wv.y, acc[0].y);
      acc[0].z = fmaf(x0.x, wv.z, acc[0].z); acc[0].w = fmaf(x0.x, wv.w, acc[0].w);
      acc[1].x = fmaf(x0.y, wv.x, acc[1].x); acc[1].y = fmaf(x0.y, wv.y, acc[1].y);
      acc[1].z = fmaf(x0.y, wv.z, acc[1].z); acc[1].w = fmaf(x0.y, wv.w, acc[1].w);
      acc[2].x = fmaf(x0.z, wv.x, acc[2].x); acc[2].y = fmaf(x0.z, wv.y, acc[2].y);
      acc[2].z = fmaf(x0.z, wv.z, acc[2].z); acc[2].w = fmaf(x0.z, wv.w, acc[2].w);
      acc[3].x = fmaf(x0.w, wv.x, acc[3].x); acc[3].y = fmaf(x0.w, wv.y, acc[3].y);
      acc[3].z = fmaf(x0.w, wv.z, acc[3].z); acc[3].w = fmaf(x0.w, wv.w, acc[3].w);
      acc[4].x = fmaf(x1.x, wv.x, acc[4].x); acc[4].y = fmaf(x1.x, wv.y, acc[4].y);
      acc[4].z = fmaf(x1.x, wv.z, acc[4].z); acc[4].w = fmaf(x1.x, wv.w, acc[4].w);
      acc[5].x = fmaf(x1.y, wv.x, acc[5].x); acc[5].y = fmaf(x1.y, wv.y, acc[5].y);
      acc[5].z = fmaf(x1.y, wv.z, acc[5].z); acc[5].w = fmaf(x1.y, wv.w, acc[5].w);
      acc[6].x = fmaf(x1.z, wv.x, acc[6].x); acc[6].y = fmaf(x1.z, wv.y, acc[6].y);
      acc[6].z = fmaf(x1.z, wv.z, acc[6].z); acc[6].w = fmaf(x1.z, wv.w, acc[6].w);
      acc[7].x = fmaf(x1.w, wv.x, acc[7].x); acc[7].y = fmaf(x1.w, wv.y, acc[7].y);
      acc[7].z = fmaf(x1.w, wv.z, acc[7].z); acc[7].w = fmaf(x1.w, wv.w, acc[7].w);
    }
  }
  #pragma unroll
  for (int i = 0; i < 8; ++i) {
    long long row = row0 + rg * 8 + i;
    if (row < N) {
      ushort4 u;
      u.x = f2bf(acc[i].x); u.y = f2bf(acc[i].y);
      u.z = f2bf(acc[i].z); u.w = f2bf(acc[i].w);
      *(ushort4*)&XWb[row * 128 + col4] = u;
    }
  }
}

// ---------- 5. aggregate ----------
__global__ __launch_bounds__(256) void aggregate_k(const unsigned short* __restrict__ XWb,
    const int* __restrict__ rowptr, const int2* __restrict__ spk,
    const float* __restrict__ dinv, const float* __restrict__ bias,
    float* __restrict__ H, int N, int relu) {
  int wid = (blockIdx.x * 256 + threadIdx.x) >> 6;  // one wave per node
  if (wid >= N) return;
  const int lane = threadIdx.x & 63;
  const int half = lane >> 5;
  const int fl = (lane & 31) * 4;
  const int beg = rowptr[wid], end = rowptr[wid + 1];
  const float di = dinv[wid];
  float a0 = 0.f, a1 = 0.f, a2 = 0.f, a3 = 0.f;
  int idx = beg;
  for (; idx + 4 <= end; idx += 4) {
    int2 rA = spk[idx + half];
    int2 rB = spk[idx + 2 + half];
    float wA = __int_as_float(rA.y);
    float wB = __int_as_float(rB.y);
    ushort4 uA = *(const ushort4*)&XWb[(long long)rA.x * 128 + fl];
    ushort4 uB = *(const ushort4*)&XWb[(long long)rB.x * 128 + fl];
    a0 += wA * bf2f(uA.x) + wB * bf2f(uB.x);
    a1 += wA * bf2f(uA.y) + wB * bf2f(uB.y);
    a2 += wA * bf2f(uA.z) + wB * bf2f(uB.z);
    a3 += wA * bf2f(uA.w) + wB * bf2f(uB.w);
  }
  if (idx < end) {
    int iA = idx + half;
    int2 rA = spk[min(iA, end - 1)];
    float wA = (iA < end) ? __int_as_float(rA.y) : 0.f;
    ushort4 uA = *(const ushort4*)&XWb[(long long)rA.x * 128 + fl];
    a0 += wA * bf2f(uA.x); a1 += wA * bf2f(uA.y);
    a2 += wA * bf2f(uA.z); a3 += wA * bf2f(uA.w);
    if (idx + 2 < end) {
      int iB = idx + 2 + half;
      int2 rB = spk[min(iB, end - 1)];
      float wB = (iB < end) ? __int_as_float(rB.y) : 0.f;
      ushort4 uB = *(const ushort4*)&XWb[(long long)rB.x * 128 + fl];
      a0 += wB * bf2f(uB.x); a1 += wB * bf2f(uB.y);
      a2 += wB * bf2f(uB.z); a3 += wB * bf2f(uB.w);
    }
  }
  a0 += __shfl_xor(a0, 32, 64);
  a1 += __shfl_xor(a1, 32, 64);
  a2 += __shfl_xor(a2, 32, 64);
  a3 += __shfl_xor(a3, 32, 64);
  if (half == 0) {
    ushort4 su = *(const ushort4*)&XWb[(long long)wid * 128 + fl];
    float d2 = di * di;
    float o0 = di * a0 + d2 * bf2f(su.x);
    float o1 = di * a1 + d2 * bf2f(su.y);
    float o2 = di * a2 + d2 * bf2f(su.z);
    float o3 = di * a3 + d2 * bf2f(su.w);
    if (bias) {
      float4 bv = *(const float4*)&bias[fl];
      o0 += bv.x; o1 += bv.y; o2 += bv.z; o3 += bv.w;
    }
    if (relu) {
      o0 = fmaxf(o0, 0.f); o1 = fmaxf(o1, 0.f);
      o2 = fmaxf(o2, 0.f); o3 = fmaxf(o3, 0.f);
    }
    *(float4*)&H[(long long)wid * 128 + fl] = make_float4(o0, o1, o2, o3);
  }
}

// ---------- 6a. pool phase A ----------
__global__ __launch_bounds__(256) void pool_partial_k(const float* __restrict__ H,
    const int* __restrict__ batch, float* __restrict__ acc, int N,
    const int* __restrict__ flags) {
  const int i64 = flags[1];
  const int lane = threadIdx.x & 63;
  const int w = threadIdx.x >> 6;
  const int chunk = (N + gridDim.x - 1) / gridDim.x;
  const int bstart = blockIdx.x * chunk;
  const int bend = min(bstart + chunk, N);
  const int sub = (chunk + 3) / 4;
  const int s = bstart + w * sub;
  const int e = min(s + sub, bend);
  if (s >= e) return;
  float ax = 0.f, ay = 0.f;
  int curg = i64 ? batch[2 * s] : batch[s];
  for (int n = s; n < e; ++n) {
    int g = i64 ? batch[2 * n] : batch[n];
    if (g != curg) {
      atomicAdd(&acc[curg * 128 + lane * 2], ax);
      atomicAdd(&acc[curg * 128 + lane * 2 + 1], ay);
      ax = ay = 0.f; curg = g;
    }
    float2 v = *(const float2*)&H[(long long)n * 128 + lane * 2];
    ax += v.x; ay += v.y;
  }
  atomicAdd(&acc[curg * 128 + lane * 2], ax);
  atomicAdd(&acc[curg * 128 + lane * 2 + 1], ay);
}

// ---------- 6b. pool finalize ----------
__global__ __launch_bounds__(128) void pool_final_k(const float* __restrict__ acc,
    const int* __restrict__ batch, const float* __restrict__ B2,
    float* __restrict__ out, int N, const int* __restrict__ flags) {
  __shared__ int sb[2];
  int g = blockIdx.x;
  int i64 = flags[1];
  if (threadIdx.x < 2) {
    int target = g + threadIdx.x;
    int lo = 0, hi = N;
    while (lo < hi) {
      int mid = (lo + hi) >> 1;
      int bv = i64 ? batch[2 * mid] : batch[mid];
      if (bv < target) lo = mid + 1; else hi = mid;
    }
    sb[threadIdx.x] = lo;
  }
  __syncthreads();
  int cnt = sb[1] - sb[0];
  int f = threadIdx.x;
  float res = 0.f;
  if (cnt > 0) res = acc[g * 128 + f] / (float)cnt + B2[f];
  out[g * 128 + f] = res;
}

extern "C" void kernel_launch(void* const* d_in, const int* in_sizes, int n_in,
                              void* d_out, int out_size, void* d_ws, size_t ws_size,
                              hipStream_t stream) {
  const int N = in_sizes[0] / 128;   // 50000
  const int E = in_sizes[1] / 2;     // 800000
  const int G = out_size / 128;      // 64
  const int NB = (N + 255) / 256;    // scan blocks
  const int NBKT = (N + 255) >> SPAN_SHIFT;  // dst buckets (196), <=256

  const void* X  = d_in[0];                       // fp32 [N,128]
  const int*  EI = (const int*)d_in[1];           // int32 or int64 [2,E]
  const int*  BA = (const int*)d_in[2];           // int32 or int64 [N] sorted
  const void* W1 = d_in[3];
  const void* B1 = d_in[4];
  const void* W2 = d_in[5];
  const void* B2 = d_in[6];
  float* OUT = (float*)d_out;                     // fp32 [G,128]

  char* ws = (char*)d_ws;
  size_t o = 0;
  auto alloc = [&](size_t b) { size_t r = o; o += (b + 255) & ~(size_t)255; return r; };
  int*   flags  = (int*)(ws + alloc(256));
  float* w1f    = (float*)(ws + alloc(16384 * 4));
  float* w2f    = (float*)(ws + alloc(16384 * 4));
  float* b1f    = (float*)(ws + alloc(128 * 4));
  float* b2f    = (float*)(ws + alloc(128 * 4));
  float* acc    = (float*)(ws + alloc((size_t)G * 128 * 4));
  int*   deg    = (int*)(ws + alloc((size_t)N * 4));
  int*   bsum   = (int*)(ws + alloc((size_t)NB * 4));
  int*   boff   = (int*)(ws + alloc((size_t)NB * 4));
  int*   bcur   = (int*)(ws + alloc(256 * 4));
  int*   rowptr = (int*)(ws + alloc((size_t)(N + 1) * 4));
  int2*  spk    = (int2*)(ws + alloc((size_t)E * 8));
  float* dinv   = (float*)(ws + alloc((size_t)N * 4));
  unsigned short* xwb = (unsigned short*)(ws + alloc((size_t)N * 128 * 2));  // bf16
  float* h1     = (float*)(ws + alloc((size_t)N * 128 * 4));
  float* h2     = h1;                 // h1 dead after gemm2 stages it
  int2*  tmp    = (int2*)h1;          // bucket-partitioned edges; h1 is dead
                                      // until aggregate1 writes it (E*8 <= N*512)

  const int TB = 256;
  detect_all_k<<<6, 256, 0, stream>>>((const unsigned short*)X, EI,
                                      (const unsigned short*)W1, (const unsigned short*)W2,
                                      (const unsigned short*)B1, (const unsigned short*)B2,
                                      flags);
  cvt_all_k<<<129, 256, 0, stream>>>(W1, W2, B1, B2, w1f, w2f, b1f, b2f, flags);

  // CSR build (shared by both layers)
  hipMemsetAsync(deg, 0, (size_t)N * 4, stream);
  hipMemsetAsync(acc, 0, (size_t)G * 128 * 4, stream);
  count_deg_k<<<(E + TB - 1) / TB, TB, 0, stream>>>(EI, deg, E, flags);
  scan1_k<<<NB, 256, 0, stream>>>(deg, bsum, N);
  scan2_k<<<1, 256, 0, stream>>>(bsum, boff, rowptr + N, NB);
  scan3_k<<<NB, 256, 0, stream>>>(deg, boff, rowptr, dinv, N);
  init_bcur_k<<<1, 256, 0, stream>>>(rowptr, bcur, N, NBKT);
  scatterA_k<<<(E + 4095) / 4096, 256, 0, stream>>>(EI, bcur, tmp, E, flags, NBKT);
  scatterB_k<<<NBKT, 256, 0, stream>>>(tmp, rowptr, dinv, spk, N);

  dim3 ggrid((N + 63) / 64);
  dim3 agrid((N * 64 + 255) / 256);

  // layer 1
  gemm_k<<<ggrid, 256, 0, stream>>>(X, w1f, xwb, N, flags, 0);
  aggregate_k<<<agrid, 256, 0, stream>>>(xwb, rowptr, spk, dinv, b1f, h1, N, 1);
  // layer 2
  gemm_k<<<ggrid, 256, 0, stream>>>(h1, w2f, xwb, N, flags, 1);
  aggregate_k<<<agrid, 256, 0, stream>>>(xwb, rowptr, spk, dinv, (const float*)nullptr, h2, N, 0);
  // pool (two-phase)
  pool_partial_k<<<512, 256, 0, stream>>>(h2, BA, acc, N, flags);
  pool_final_k<<<G, 128, 0, stream>>>(acc, BA, b2f, OUT, N, flags);
}

// Round 8
// 305.404 us; speedup vs baseline: 2.2869x; 1.0847x over previous
//
#include <hip/hip_runtime.h>
#include <hip/hip_bf16.h>

#define SPAN_SHIFT 8   // dst-bucket span = 256 nodes

typedef __attribute__((ext_vector_type(8))) short short8;
typedef __attribute__((ext_vector_type(4))) float float4v;

// ---------- bf16 helpers (OCP bf16 = fp32 upper 16 bits) ----------
__device__ __forceinline__ float bf2f(unsigned short u) {
  union { unsigned int i; float f; } v; v.i = ((unsigned int)u) << 16; return v.f;
}
__device__ __forceinline__ unsigned short f2bf(float f) {
  union { float f; unsigned int i; } v; v.f = f;
  unsigned int x = v.i;
  return (unsigned short)((x + 0x7fffu + ((x >> 16) & 1u)) >> 16);  // RNE
}

// ---------- 0. per-tensor runtime dtype detection ----------
__global__ __launch_bounds__(256) void detect_all_k(
    const unsigned short* __restrict__ xu,  const int* __restrict__ ei,
    const unsigned short* __restrict__ w1u, const unsigned short* __restrict__ w2u,
    const unsigned short* __restrict__ b1u, const unsigned short* __restrict__ b2u,
    int* __restrict__ flags) {
  __shared__ int s_cnt;
  if (threadIdx.x == 0) s_cnt = 0;
  __syncthreads();
  const int b = blockIdx.x;
  int cnt = 0;
  if (b == 1) {  // int width: high words of int64 positives are all zero
    for (int i = threadIdx.x; i < 4096; i += 256)
      if (ei[2 * i + 1] == 0) cnt++;
    atomicAdd(&s_cnt, cnt);
    __syncthreads();
    if (threadIdx.x == 0) flags[1] = (s_cnt > 2048) ? 1 : 0;
    return;
  }
  const unsigned short* p; int n; int fi;
  if (b == 0)      { p = xu;  n = 16384; fi = 0; }
  else if (b == 2) { p = w1u; n = 16384; fi = 2; }
  else if (b == 3) { p = w2u; n = 16384; fi = 3; }
  else if (b == 4) { p = b1u; n = 128;   fi = 4; }
  else             { p = b2u; n = 128;   fi = 5; }
  for (int i = threadIdx.x; i < n; i += 256) {
    int e = (p[i] >> 7) & 0xFF;
    if (e < 96 || e > 159) cnt++;   // wild bf16 exponent => fp32 data
  }
  atomicAdd(&s_cnt, cnt);
  __syncthreads();
  if (threadIdx.x == 0) flags[fi] = (s_cnt * 8 > n) ? 1 : 0;
}

// ---------- merged param convert: anything -> fp32 ----------
__global__ __launch_bounds__(256) void cvt_all_k(
    const void* __restrict__ W1, const void* __restrict__ W2,
    const void* __restrict__ B1, const void* __restrict__ B2,
    float* __restrict__ w1f, float* __restrict__ w2f,
    float* __restrict__ b1f, float* __restrict__ b2f,
    const int* __restrict__ flags) {
  int b = blockIdx.x;
  if (b < 64) {
    int i = b * 256 + threadIdx.x;
    w1f[i] = flags[2] ? ((const float*)W1)[i] : bf2f(((const unsigned short*)W1)[i]);
  } else if (b < 128) {
    int i = (b - 64) * 256 + threadIdx.x;
    w2f[i] = flags[3] ? ((const float*)W2)[i] : bf2f(((const unsigned short*)W2)[i]);
  } else {
    if (threadIdx.x < 128)
      b1f[threadIdx.x] = flags[4] ? ((const float*)B1)[threadIdx.x]
                                  : bf2f(((const unsigned short*)B1)[threadIdx.x]);
    else {
      int i = threadIdx.x - 128;
      b2f[i] = flags[5] ? ((const float*)B2)[i] : bf2f(((const unsigned short*)B2)[i]);
    }
  }
}

// ---------- 1. degree count ----------
__global__ void count_deg_k(const int* __restrict__ ei, int* __restrict__ deg, int E,
                            const int* __restrict__ flags) {
  int e = blockIdx.x * blockDim.x + threadIdx.x;
  if (e >= E) return;
  int d = flags[1] ? ei[2 * (E + e)] : ei[E + e];
  atomicAdd(&deg[d], 1);
}

// ---------- 2. hierarchical exclusive scan ----------
__global__ __launch_bounds__(256) void scan1_k(const int* __restrict__ deg,
                                               int* __restrict__ bsum, int N) {
  __shared__ int red[4];
  int i = blockIdx.x * 256 + threadIdx.x;
  int v = (i < N) ? deg[i] : 0;
  int lane = threadIdx.x & 63, w = threadIdx.x >> 6;
  #pragma unroll
  for (int off = 32; off > 0; off >>= 1) v += __shfl_down(v, off, 64);
  if (lane == 0) red[w] = v;
  __syncthreads();
  if (threadIdx.x == 0) bsum[blockIdx.x] = red[0] + red[1] + red[2] + red[3];
}
__global__ __launch_bounds__(256) void scan2_k(const int* __restrict__ bsum,
                                               int* __restrict__ boff,
                                               int* __restrict__ rowptrN, int nb) {
  __shared__ int ws[4];
  const int tid = threadIdx.x, lane = tid & 63, w = tid >> 6;
  int carry = 0;
  for (int base = 0; base < nb; base += 256) {
    int i = base + tid;
    int v = (i < nb) ? bsum[i] : 0;
    int inc = v;
    #pragma unroll
    for (int off = 1; off < 64; off <<= 1) {
      int n = __shfl_up(inc, off, 64);
      if (lane >= off) inc += n;
    }
    if (lane == 63) ws[w] = inc;
    __syncthreads();
    int woff = 0, tot = 0;
    #pragma unroll
    for (int k = 0; k < 4; ++k) { int s = ws[k]; if (k < w) woff += s; tot += s; }
    if (i < nb) boff[i] = carry + woff + inc - v;
    carry += tot;
    __syncthreads();
  }
  if (tid == 0) *rowptrN = carry;
}
__global__ __launch_bounds__(256) void scan3_k(const int* __restrict__ deg,
                                               const int* __restrict__ boff,
                                               int* __restrict__ rowptr,
                                               float* __restrict__ dinv, int N) {
  __shared__ int ws[4];
  int i = blockIdx.x * 256 + threadIdx.x;
  int lane = threadIdx.x & 63, w = threadIdx.x >> 6;
  int v = (i < N) ? deg[i] : 0;
  int inc = v;
  #pragma unroll
  for (int off = 1; off < 64; off <<= 1) {
    int n = __shfl_up(inc, off, 64);
    if (lane >= off) inc += n;
  }
  if (lane == 63) ws[w] = inc;
  __syncthreads();
  int woff = 0;
  #pragma unroll
  for (int k = 0; k < 4; ++k) if (k < w) woff += ws[k];
  if (i < N) {
    rowptr[i] = boff[blockIdx.x] + woff + inc - v;
    dinv[i] = rsqrtf((float)(v + 1));  // +1 self-loop
  }
}

// ---------- 3a. bucket cursor init ----------
__global__ void init_bcur_k(const int* __restrict__ rowptr, int* __restrict__ bcur,
                            int N, int NBKT) {
  int t = blockIdx.x * blockDim.x + threadIdx.x;
  if (t < NBKT) bcur[t] = rowptr[min(t << SPAN_SHIFT, N)];
}

// ---------- 3b. pass A: LDS radix-partition edges into dst-buckets ----------
__global__ __launch_bounds__(256) void scatterA_k(const int* __restrict__ ei,
    int* __restrict__ bcur, int2* __restrict__ tmp, int E,
    const int* __restrict__ flags, int NBKT) {
  __shared__ int2 stage[4096];                 // 32 KB
  __shared__ int hist[256], off[256], cnt2[256], gbase[256];
  __shared__ int wsum[4];
  const int tid = threadIdx.x;
  hist[tid] = 0; cnt2[tid] = 0;
  __syncthreads();
  const int base = blockIdx.x * 4096;
  const int i64 = flags[1];
  int rs[16], rd[16];
  #pragma unroll
  for (int j = 0; j < 16; ++j) {
    int e = base + j * 256 + tid;
    if (e < E) {
      int s, d;
      if (i64) { s = ei[2 * e]; d = ei[2 * (E + e)]; }
      else     { s = ei[e];     d = ei[E + e]; }
      rs[j] = s; rd[j] = d;
      atomicAdd(&hist[d >> SPAN_SHIFT], 1);
    } else rd[j] = -1;
  }
  __syncthreads();
  {
    int lane = tid & 63, w = tid >> 6;
    int v = hist[tid], inc = v;
    #pragma unroll
    for (int o = 1; o < 64; o <<= 1) { int n = __shfl_up(inc, o, 64); if (lane >= o) inc += n; }
    if (lane == 63) wsum[w] = inc;
    __syncthreads();
    int pre = 0;
    #pragma unroll
    for (int k = 0; k < 4; ++k) if (k < w) pre += wsum[k];
    off[tid] = pre + inc - v;
  }
  __syncthreads();
  #pragma unroll
  for (int j = 0; j < 16; ++j) {
    if (rd[j] >= 0) {
      int b = rd[j] >> SPAN_SHIFT;
      int r = atomicAdd(&cnt2[b], 1);
      int2 rec; rec.x = rs[j]; rec.y = rd[j];
      stage[off[b] + r] = rec;
    }
  }
  if (tid < NBKT && hist[tid] > 0) gbase[tid] = atomicAdd(&bcur[tid], hist[tid]);
  __syncthreads();
  const int total = off[255] + hist[255];
  for (int i = tid; i < total; i += 256) {
    int2 rec = stage[i];
    int b = rec.y >> SPAN_SHIFT;
    tmp[gbase[b] + (i - off[b])] = rec;
  }
}

// ---------- 3c. pass B: one block per bucket -> final CSR ----------
__global__ __launch_bounds__(256) void scatterB_k(const int2* __restrict__ tmp,
    const int* __restrict__ rowptr, const float* __restrict__ dinv,
    int2* __restrict__ spk, int N) {
  __shared__ int cur[256];
  const int tid = threadIdx.x;
  const int n0 = blockIdx.x << SPAN_SHIFT;
  const int n1 = min(n0 + 256, N);
  if (n0 + tid < n1) cur[tid] = rowptr[n0 + tid];
  __syncthreads();
  const int e0 = rowptr[n0], e1 = rowptr[n1];
  for (int i = e0 + tid; i < e1; i += 256) {
    int2 rec = tmp[i];
    int pos = atomicAdd(&cur[rec.y - n0], 1);
    int2 out; out.x = rec.x; out.y = __float_as_int(dinv[rec.x]);
    spk[pos] = out;
  }
}

// ---------- 4. MFMA GEMM: XWb[N,128](bf16) = X[N,128] @ W[128,128] ----------
// Block = 64 rows, 4 waves (16 rows each). mfma_f32_16x16x32_bf16.
// Verified layouts: A[m=lane&15][k=quad*8+j]; C/D col=lane&15,row=quad*4+reg.
// W staged pre-swizzled so each B-frag (n=lane&15, k=quad*8+j) is one b128.
__global__ __launch_bounds__(256) void gemm_k(const void* __restrict__ X,
                                              const float* __restrict__ Wf,
                                              unsigned short* __restrict__ XWb, int N,
                                              const int* __restrict__ flags, int xmode) {
  __shared__ unsigned short Wl[16384];     // swizzled frags, 32 KB
  __shared__ unsigned short Xl[64 * 136];  // row-major bf16, pad +8, 17.4 KB
  const int tid = threadIdx.x;
  const int xf32 = xmode ? 1 : flags[0];
  const int row0 = blockIdx.x * 64;
  // stage W: coalesced fp32 reads, swizzled bf16 LDS writes
  for (int v = tid; v < 4096; v += 256) {
    int k = v >> 5, n4 = (v & 31) * 4;
    float4 w4 = *(const float4*)&Wf[k * 128 + n4];
    int c = k >> 5, quad = (k >> 3) & 3, j = k & 7;
    float wa0 = w4.x, wa1 = w4.y, wa2 = w4.z, wa3 = w4.w;
    int t = n4 >> 4;                        // n4..n4+3 stay within one 16-tile
    int colb = n4 & 15;
    int bb = ((c * 8 + t) * 64 + quad * 16 + colb) * 8 + j;
    Wl[bb]      = f2bf(wa0);
    Wl[bb + 8]  = f2bf(wa1);
    Wl[bb + 16] = f2bf(wa2);
    Wl[bb + 24] = f2bf(wa3);
  }
  // stage X rows (64 x 128) as bf16, row-major padded
  for (int v = tid; v < 2048; v += 256) {
    int r = v >> 5, k4 = (v & 31) * 4;
    int row = row0 + r;
    ushort4 u = make_ushort4(0, 0, 0, 0);
    if (row < N) {
      long long gi = (long long)row * 128 + k4;
      if (xf32) {
        float4 xv = *(const float4*)&((const float*)X)[gi];
        u.x = f2bf(xv.x); u.y = f2bf(xv.y); u.z = f2bf(xv.z); u.w = f2bf(xv.w);
      } else {
        u = *(const ushort4*)&((const unsigned short*)X)[gi];
      }
    }
    *(ushort4*)&Xl[r * 136 + k4] = u;
  }
  __syncthreads();
  const int w = tid >> 6, lane = tid & 63;
  const int quad = lane >> 4, col = lane & 15;
  float4v acc[8];
  #pragma unroll
  for (int t = 0; t < 8; ++t) acc[t] = (float4v){0.f, 0.f, 0.f, 0.f};
  #pragma unroll
  for (int c = 0; c < 4; ++c) {
    short8 a = *(const short8*)&Xl[(w * 16 + col) * 136 + c * 32 + quad * 8];
    #pragma unroll
    for (int t = 0; t < 8; ++t) {
      short8 b = *(const short8*)&Wl[((c * 8 + t) * 64 + lane) * 8];
      acc[t] = __builtin_amdgcn_mfma_f32_16x16x32_bf16(a, b, acc[t], 0, 0, 0);
    }
  }
  // store: C/D col=lane&15, row=quad*4+reg
  #pragma unroll
  for (int t = 0; t < 8; ++t) {
    #pragma unroll
    for (int r = 0; r < 4; ++r) {
      int row = row0 + w * 16 + quad * 4 + r;
      if (row < N) XWb[(long long)row * 128 + t * 16 + col] = f2bf(acc[t][r]);
    }
  }
}

// ---------- 5. aggregate: 8-edge unroll, 4 gathers in flight ----------
__global__ __launch_bounds__(256) void aggregate_k(const unsigned short* __restrict__ XWb,
    const int* __restrict__ rowptr, const int2* __restrict__ spk,
    const float* __restrict__ dinv, const float* __restrict__ bias,
    float* __restrict__ H, int N, int relu) {
  int wid = (blockIdx.x * 256 + threadIdx.x) >> 6;  // one wave per node
  if (wid >= N) return;
  const int lane = threadIdx.x & 63;
  const int half = lane >> 5;
  const int fl = (lane & 31) * 4;
  const int beg = rowptr[wid], end = rowptr[wid + 1];
  const float di = dinv[wid];
  float a0 = 0.f, a1 = 0.f, a2 = 0.f, a3 = 0.f;
  int idx = beg;
  for (; idx + 8 <= end; idx += 8) {
    int2 rA = spk[idx + half];
    int2 rB = spk[idx + 2 + half];
    int2 rC = spk[idx + 4 + half];
    int2 rD = spk[idx + 6 + half];
    float wA = __int_as_float(rA.y), wB = __int_as_float(rB.y);
    float wC = __int_as_float(rC.y), wD = __int_as_float(rD.y);
    ushort4 uA = *(const ushort4*)&XWb[(long long)rA.x * 128 + fl];
    ushort4 uB = *(const ushort4*)&XWb[(long long)rB.x * 128 + fl];
    ushort4 uC = *(const ushort4*)&XWb[(long long)rC.x * 128 + fl];
    ushort4 uD = *(const ushort4*)&XWb[(long long)rD.x * 128 + fl];
    a0 += wA * bf2f(uA.x) + wB * bf2f(uB.x) + wC * bf2f(uC.x) + wD * bf2f(uD.x);
    a1 += wA * bf2f(uA.y) + wB * bf2f(uB.y) + wC * bf2f(uC.y) + wD * bf2f(uD.y);
    a2 += wA * bf2f(uA.z) + wB * bf2f(uB.z) + wC * bf2f(uC.z) + wD * bf2f(uD.z);
    a3 += wA * bf2f(uA.w) + wB * bf2f(uB.w) + wC * bf2f(uC.w) + wD * bf2f(uD.w);
  }
  if (idx + 4 <= end) {
    int2 rA = spk[idx + half];
    int2 rB = spk[idx + 2 + half];
    float wA = __int_as_float(rA.y), wB = __int_as_float(rB.y);
    ushort4 uA = *(const ushort4*)&XWb[(long long)rA.x * 128 + fl];
    ushort4 uB = *(const ushort4*)&XWb[(long long)rB.x * 128 + fl];
    a0 += wA * bf2f(uA.x) + wB * bf2f(uB.x);
    a1 += wA * bf2f(uA.y) + wB * bf2f(uB.y);
    a2 += wA * bf2f(uA.z) + wB * bf2f(uB.z);
    a3 += wA * bf2f(uA.w) + wB * bf2f(uB.w);
    idx += 4;
  }
  if (idx < end) {
    int iA = idx + half;
    int2 rA = spk[min(iA, end - 1)];
    float wA = (iA < end) ? __int_as_float(rA.y) : 0.f;
    ushort4 uA = *(const ushort4*)&XWb[(long long)rA.x * 128 + fl];
    a0 += wA * bf2f(uA.x); a1 += wA * bf2f(uA.y);
    a2 += wA * bf2f(uA.z); a3 += wA * bf2f(uA.w);
    if (idx + 2 < end) {
      int iB = idx + 2 + half;
      int2 rB = spk[min(iB, end - 1)];
      float wB = (iB < end) ? __int_as_float(rB.y) : 0.f;
      ushort4 uB = *(const ushort4*)&XWb[(long long)rB.x * 128 + fl];
      a0 += wB * bf2f(uB.x); a1 += wB * bf2f(uB.y);
      a2 += wB * bf2f(uB.z); a3 += wB * bf2f(uB.w);
    }
  }
  a0 += __shfl_xor(a0, 32, 64);
  a1 += __shfl_xor(a1, 32, 64);
  a2 += __shfl_xor(a2, 32, 64);
  a3 += __shfl_xor(a3, 32, 64);
  if (half == 0) {
    ushort4 su = *(const ushort4*)&XWb[(long long)wid * 128 + fl];
    float d2 = di * di;
    float o0 = di * a0 + d2 * bf2f(su.x);
    float o1 = di * a1 + d2 * bf2f(su.y);
    float o2 = di * a2 + d2 * bf2f(su.z);
    float o3 = di * a3 + d2 * bf2f(su.w);
    if (bias) {
      float4 bv = *(const float4*)&bias[fl];
      o0 += bv.x; o1 += bv.y; o2 += bv.z; o3 += bv.w;
    }
    if (relu) {
      o0 = fmaxf(o0, 0.f); o1 = fmaxf(o1, 0.f);
      o2 = fmaxf(o2, 0.f); o3 = fmaxf(o3, 0.f);
    }
    *(float4*)&H[(long long)wid * 128 + fl] = make_float4(o0, o1, o2, o3);
  }
}

// ---------- 6a. pool phase A ----------
__global__ __launch_bounds__(256) void pool_partial_k(const float* __restrict__ H,
    const int* __restrict__ batch, float* __restrict__ acc, int N,
    const int* __restrict__ flags) {
  const int i64 = flags[1];
  const int lane = threadIdx.x & 63;
  const int w = threadIdx.x >> 6;
  const int chunk = (N + gridDim.x - 1) / gridDim.x;
  const int bstart = blockIdx.x * chunk;
  const int bend = min(bstart + chunk, N);
  const int sub = (chunk + 3) / 4;
  const int s = bstart + w * sub;
  const int e = min(s + sub, bend);
  if (s >= e) return;
  float ax = 0.f, ay = 0.f;
  int curg = i64 ? batch[2 * s] : batch[s];
  for (int n = s; n < e; ++n) {
    int g = i64 ? batch[2 * n] : batch[n];
    if (g != curg) {
      atomicAdd(&acc[curg * 128 + lane * 2], ax);
      atomicAdd(&acc[curg * 128 + lane * 2 + 1], ay);
      ax = ay = 0.f; curg = g;
    }
    float2 v = *(const float2*)&H[(long long)n * 128 + lane * 2];
    ax += v.x; ay += v.y;
  }
  atomicAdd(&acc[curg * 128 + lane * 2], ax);
  atomicAdd(&acc[curg * 128 + lane * 2 + 1], ay);
}

// ---------- 6b. pool finalize ----------
__global__ __launch_bounds__(128) void pool_final_k(const float* __restrict__ acc,
    const int* __restrict__ batch, const float* __restrict__ B2,
    float* __restrict__ out, int N, const int* __restrict__ flags) {
  __shared__ int sb[2];
  int g = blockIdx.x;
  int i64 = flags[1];
  if (threadIdx.x < 2) {
    int target = g + threadIdx.x;
    int lo = 0, hi = N;
    while (lo < hi) {
      int mid = (lo + hi) >> 1;
      int bv = i64 ? batch[2 * mid] : batch[mid];
      if (bv < target) lo = mid + 1; else hi = mid;
    }
    sb[threadIdx.x] = lo;
  }
  __syncthreads();
  int cnt = sb[1] - sb[0];
  int f = threadIdx.x;
  float res = 0.f;
  if (cnt > 0) res = acc[g * 128 + f] / (float)cnt + B2[f];
  out[g * 128 + f] = res;
}

extern "C" void kernel_launch(void* const* d_in, const int* in_sizes, int n_in,
                              void* d_out, int out_size, void* d_ws, size_t ws_size,
                              hipStream_t stream) {
  const int N = in_sizes[0] / 128;   // 50000
  const int E = in_sizes[1] / 2;     // 800000
  const int G = out_size / 128;      // 64
  const int NB = (N + 255) / 256;
  const int NBKT = (N + 255) >> SPAN_SHIFT;

  const void* X  = d_in[0];
  const int*  EI = (const int*)d_in[1];
  const int*  BA = (const int*)d_in[2];
  const void* W1 = d_in[3];
  const void* B1 = d_in[4];
  const void* W2 = d_in[5];
  const void* B2 = d_in[6];
  float* OUT = (float*)d_out;

  char* ws = (char*)d_ws;
  size_t o = 0;
  auto alloc = [&](size_t b) { size_t r = o; o += (b + 255) & ~(size_t)255; return r; };
  int*   flags  = (int*)(ws + alloc(256));
  float* w1f    = (float*)(ws + alloc(16384 * 4));
  float* w2f    = (float*)(ws + alloc(16384 * 4));
  float* b1f    = (float*)(ws + alloc(128 * 4));
  float* b2f    = (float*)(ws + alloc(128 * 4));
  float* acc    = (float*)(ws + alloc((size_t)G * 128 * 4));
  int*   deg    = (int*)(ws + alloc((size_t)N * 4));
  int*   bsum   = (int*)(ws + alloc((size_t)NB * 4));
  int*   boff   = (int*)(ws + alloc((size_t)NB * 4));
  int*   bcur   = (int*)(ws + alloc(256 * 4));
  int*   rowptr = (int*)(ws + alloc((size_t)(N + 1) * 4));
  int2*  spk    = (int2*)(ws + alloc((size_t)E * 8));
  float* dinv   = (float*)(ws + alloc((size_t)N * 4));
  unsigned short* xwb = (unsigned short*)(ws + alloc((size_t)N * 128 * 2));
  float* h1     = (float*)(ws + alloc((size_t)N * 128 * 4));
  float* h2     = h1;                 // h1 dead after gemm2 stages it
  int2*  tmp    = (int2*)h1;          // bucket-partitioned edges; dead before aggregate1

  const int TB = 256;
  detect_all_k<<<6, 256, 0, stream>>>((const unsigned short*)X, EI,
                                      (const unsigned short*)W1, (const unsigned short*)W2,
                                      (const unsigned short*)B1, (const unsigned short*)B2,
                                      flags);
  cvt_all_k<<<129, 256, 0, stream>>>(W1, W2, B1, B2, w1f, w2f, b1f, b2f, flags);

  hipMemsetAsync(deg, 0, (size_t)N * 4, stream);
  hipMemsetAsync(acc, 0, (size_t)G * 128 * 4, stream);
  count_deg_k<<<(E + TB - 1) / TB, TB, 0, stream>>>(EI, deg, E, flags);
  scan1_k<<<NB, 256, 0, stream>>>(deg, bsum, N);
  scan2_k<<<1, 256, 0, stream>>>(bsum, boff, rowptr + N, NB);
  scan3_k<<<NB, 256, 0, stream>>>(deg, boff, rowptr, dinv, N);
  init_bcur_k<<<1, 256, 0, stream>>>(rowptr, bcur, N, NBKT);
  scatterA_k<<<(E + 4095) / 4096, 256, 0, stream>>>(EI, bcur, tmp, E, flags, NBKT);
  scatterB_k<<<NBKT, 256, 0, stream>>>(tmp, rowptr, dinv, spk, N);

  dim3 ggrid((N + 63) / 64);
  dim3 agrid((N * 64 + 255) / 256);

  // layer 1
  gemm_k<<<ggrid, 256, 0, stream>>>(X, w1f, xwb, N, flags, 0);
  aggregate_k<<<agrid, 256, 0, stream>>>(xwb, rowptr, spk, dinv, b1f, h1, N, 1);
  // layer 2
  gemm_k<<<ggrid, 256, 0, stream>>>(h1, w2f, xwb, N, flags, 1);
  aggregate_k<<<agrid, 256, 0, stream>>>(xwb, rowptr, spk, dinv, (const float*)nullptr, h2, N, 0);
  // pool (two-phase)
  pool_partial_k<<<512, 256, 0, stream>>>(h2, BA, acc, N, flags);
  pool_final_k<<<G, 128, 0, stream>>>(acc, BA, b2f, OUT, N, flags);
}